// Round 11
// baseline (115.452 us; speedup 1.0000x reference)
//
#include <hip/hip_runtime.h>
#include <hip/hip_bf16.h>
#include <stdint.h>

#define TS 1024   // T
#define CS 1024   // C
#define NH 16
#define DHEAD 64
#define NBATCH 2
#define EPSV 1e-5f
#define MEG 1048576

typedef __bf16 bf16x8 __attribute__((ext_vector_type(8)));
typedef float  f32x4  __attribute__((ext_vector_type(4)));

#define MFMA(a, b, c) __builtin_amdgcn_mfma_f32_16x16x32_bf16((a), (b), (c), 0, 0, 0)

__device__ __forceinline__ float bf2f(ushort u){
  union { uint32_t i; float f; } v; v.i = ((uint32_t)u) << 16; return v.f;
}
__device__ __forceinline__ ushort f2bf(float f){
  union { float f; uint32_t i; } v; v.f = f;
  uint32_t r = v.i + 0x7FFFu + ((v.i >> 16) & 1u);
  return (ushort)(r >> 16);
}

// async global->LDS, 16B per lane. LDS dest wave-uniform base + lane*16B (linear);
// global src per-lane (enables pre-swizzled-source LDS layouts).
__device__ __forceinline__ void gl_lds16(const ushort* g, ushort* l) {
  __builtin_amdgcn_global_load_lds(
      (const __attribute__((address_space(1))) void*)g,
      (__attribute__((address_space(3))) void*)l, 16, 0, 0);
}

// ---------------- fused cast fp32 -> bf16 of all 7 tensors ----------------
__global__ __launch_bounds__(256)
void cast_all(const float* __restrict__ x,
              const float* __restrict__ Wq, const float* __restrict__ Wk,
              const float* __restrict__ Wv, const float* __restrict__ Wq2,
              const float* __restrict__ Wk2, const float* __restrict__ Wo,
              ushort* __restrict__ xb, ushort* __restrict__ wcat)
{
  const int XC = 524288, TOT = 2097152;
  for (int idx = blockIdx.x * 256 + threadIdx.x; idx < TOT; idx += 524288) {
    const float* s; ushort* d; int c;
    if (idx < XC) { s = x; d = xb; c = idx; }
    else {
      int r = idx - XC; int w = r >> 18; c = r & 262143;
      switch (w) {
        case 0:  s = Wq;  d = wcat;           break;
        case 1:  s = Wk;  d = wcat + 1*MEG;   break;
        case 2:  s = Wv;  d = wcat + 4*MEG;   break;
        case 3:  s = Wq2; d = wcat + 2*MEG;   break;
        case 4:  s = Wk2; d = wcat + 3*MEG;   break;
        default: s = Wo;  d = wcat + 5*MEG;   break;
      }
    }
    float4 v = *(const float4*)(s + (size_t)c * 4);
    ushort4 o; o.x = f2bf(v.x); o.y = f2bf(v.y); o.z = f2bf(v.z); o.w = f2bf(v.w);
    *(ushort4*)(d + (size_t)c * 4) = o;
  }
}

#define BM 128
#define BN 128

// ---------------- fused projection GEMM: [x]@[Wq;Wk;Wq2;Wk2;Wv]^T ----------------
// v4: BM=128 x BN=128, BK=64, DOUBLE-BUFFERED LDS + prefetch-ahead:
// per iter: issue stage(t+1) -> compute(t) -> ONE barrier. The vmcnt(0) drain
// at the barrier now lands AFTER compute, so load latency hides under MFMA
// (same restructure that took attn 83.8 -> 48.6 us in R5). Granule-XOR swizzle.
__global__ __launch_bounds__(256, 2)
void gemm_proj(const ushort* __restrict__ A, const ushort* __restrict__ Bt,
               ushort* __restrict__ qb, ushort* __restrict__ kb,
               ushort* __restrict__ q2b, ushort* __restrict__ k2b,
               ushort* __restrict__ vtb,
               ushort* __restrict__ ktb, ushort* __restrict__ k2tb)
{
  __shared__ ushort a_s[2][BM * 64];   // 2 x 16KB, [128 rows][64 cols] swz g^=row&7
  __shared__ ushort b_s[2][BN * 64];   // 2 x 16KB

  const int n0 = blockIdx.x * BN;
  const int m0 = blockIdx.y * BM;

  const int t  = threadIdx.x;
  const int w  = t >> 6, l = t & 63;
  const int wr = w >> 1, wc = w & 1;
  const int l15 = l & 15, l4 = l >> 4;
  const int r8 = l >> 3, g7 = l & 7;

  auto stage = [&](int kt, int bs) {
    const int k0 = kt * 64;
    #pragma unroll
    for (int i = 0; i < 4; ++i) {
      int issue = w * 4 + i;              // 0..15
      int row   = issue * 8 + r8;         // 0..127
      int gs    = g7 ^ (row & 7);
      gl_lds16(&A [(size_t)(m0 + row) * CS + k0 + gs * 8], &a_s[bs][issue * 512]);
      gl_lds16(&Bt[(size_t)(n0 + row) * CS + k0 + gs * 8], &b_s[bs][issue * 512]);
    }
  };

  f32x4 acc[4][4] = {};

  stage(0, 0);
  __syncthreads();

  for (int kt = 0; kt < 16; ++kt) {
    const int cur = kt & 1;
    if (kt < 15) stage(kt + 1, cur ^ 1);

    #pragma unroll
    for (int ks = 0; ks < 2; ++ks) {
      bf16x8 af[4], bfr[4];
      #pragma unroll
      for (int mi = 0; mi < 4; ++mi) {
        int row = wr * 64 + mi * 16 + l15;
        int gl  = (ks * 4 + l4) ^ (row & 7);
        af[mi] = *(const bf16x8*)&a_s[cur][row * 64 + gl * 8];
      }
      #pragma unroll
      for (int ni = 0; ni < 4; ++ni) {
        int row = wc * 64 + ni * 16 + l15;
        int gl  = (ks * 4 + l4) ^ (row & 7);
        bfr[ni] = *(const bf16x8*)&b_s[cur][row * 64 + gl * 8];
      }
      #pragma unroll
      for (int mi = 0; mi < 4; ++mi)
        #pragma unroll
        for (int ni = 0; ni < 4; ++ni)
          acc[mi][ni] = MFMA(af[mi], bfr[ni], acc[mi][ni]);
    }

    __syncthreads();   // drains prefetch (issued pre-compute) + releases cur
  }

  #pragma unroll
  for (int mi = 0; mi < 4; ++mi) {
    #pragma unroll
    for (int ni = 0; ni < 4; ++ni) {
      int col  = n0 + wc * 64 + ni * 16 + l15;
      int row0 = m0 + wr * 64 + mi * 16 + l4 * 4;
      int seg  = col >> 10, cc = col & (CS - 1);
      if (seg < 4) {
        ushort* dst = (seg == 0) ? qb : (seg == 1) ? kb : (seg == 2) ? q2b : k2b;
        float sc = (seg & 1) ? 1.f : 0.125f;   // fold 1/sqrt(Dh) into q, q2
        #pragma unroll
        for (int e = 0; e < 4; ++e)
          dst[(size_t)(row0 + e) * CS + cc] = f2bf(acc[mi][ni][e] * sc);
        if (seg == 1 || seg == 3) {
          int bb = row0 >> 10, tt = row0 & (TS - 1);
          int hh = cc >> 6, dd = cc & (DHEAD - 1);
          ushort* td = (seg == 1) ? ktb : k2tb;
          ushort4 o;
          o.x = f2bf(acc[mi][ni][0]); o.y = f2bf(acc[mi][ni][1]);
          o.z = f2bf(acc[mi][ni][2]); o.w = f2bf(acc[mi][ni][3]);
          *(ushort4*)&td[(((size_t)(bb * NH + hh) * DHEAD + dd) * TS) + tt] = o;
        }
      } else {
        int bb = row0 >> 10, tt = row0 & (TS - 1);
        int hh = cc >> 6, dd = cc & (DHEAD - 1);
        ushort4 o;
        o.x = f2bf(acc[mi][ni][0]); o.y = f2bf(acc[mi][ni][1]);
        o.z = f2bf(acc[mi][ni][2]); o.w = f2bf(acc[mi][ni][3]);
        *(ushort4*)&vtb[(((size_t)(bb * NH + hh) * DHEAD + dd) * TS) + tt] = o;
      }
    }
  }
}

// ---------------- out-projection GEMM: out = y @ Wo^T (fp32 out) --------------
// v3: 64x64 tile, BK=32, DOUBLE-BUFFERED + prefetch-ahead (1 barrier/iter).
// Grid 512 (2 blocks/CU), 1D XCD-swizzled.
__global__ __launch_bounds__(256, 2)
void gemm_out(const ushort* __restrict__ A, const ushort* __restrict__ Bt,
              float* __restrict__ C)
{
  __shared__ ushort a_s[2][64 * 32];
  __shared__ ushort b_s[2][64 * 32];

  const int bid = blockIdx.x;
  const int s   = (bid & 7) * 64 + (bid >> 3);    // bijective, 512%8==0
  const int n0  = (s >> 5) * 64;
  const int m0  = (s & 31) * 64;

  const int t  = threadIdx.x;
  const int w  = t >> 6, l = t & 63;
  const int wr = w >> 1, wc = w & 1;
  const int l15 = l & 15, l4 = l >> 4;
  const int rs = l >> 2;
  const int c8 = (l & 3) * 8;

  auto stage = [&](int kt, int bs) {
    const int k0 = kt * 32;
    gl_lds16(&A [(size_t)(m0 + w * 16 + rs) * CS + k0 + c8], &a_s[bs][w * 512]);
    gl_lds16(&Bt[(size_t)(n0 + w * 16 + rs) * CS + k0 + c8], &b_s[bs][w * 512]);
  };

  f32x4 acc[2][2] = {};

  stage(0, 0);
  __syncthreads();

  for (int kt = 0; kt < 32; ++kt) {
    const int cur = kt & 1;
    if (kt < 31) stage(kt + 1, cur ^ 1);

    bf16x8 af[2], bfr[2];
    #pragma unroll
    for (int mi = 0; mi < 2; ++mi)
      af[mi] = *(const bf16x8*)&a_s[cur][(wr * 32 + mi * 16 + l15) * 32 + l4 * 8];
    #pragma unroll
    for (int ni = 0; ni < 2; ++ni)
      bfr[ni] = *(const bf16x8*)&b_s[cur][(wc * 32 + ni * 16 + l15) * 32 + l4 * 8];

    #pragma unroll
    for (int mi = 0; mi < 2; ++mi)
      #pragma unroll
      for (int ni = 0; ni < 2; ++ni)
        acc[mi][ni] = MFMA(af[mi], bfr[ni], acc[mi][ni]);

    __syncthreads();   // drains prefetch + releases cur
  }

  #pragma unroll
  for (int mi = 0; mi < 2; ++mi)
    #pragma unroll
    for (int ni = 0; ni < 2; ++ni)
      #pragma unroll
      for (int e = 0; e < 4; ++e)
        C[(size_t)(m0 + wr * 32 + mi * 16 + l4 * 4 + e) * CS +
          n0 + wc * 32 + ni * 16 + l15] = acc[mi][ni][e];
}

// ---------------- Gram kernel: G = K^T K (64x64, bf16 out) + colsum(K) ----------
__global__ __launch_bounds__(256, 2)
void gram(const ushort* __restrict__ ktb, const ushort* __restrict__ k2tb,
          ushort* __restrict__ g1b, ushort* __restrict__ g2b,
          float* __restrict__ csb)
{
  __shared__ ushort t_s[64 * 128];   // [64 d][128 t], granule-swizzled g ^= d&15

  const int mat = blockIdx.x & 1, z = blockIdx.x >> 1;
  const ushort* S = (mat ? k2tb : ktb) + (size_t)z * DHEAD * TS;

  const int t = threadIdx.x, w = t >> 6, l = t & 63;
  const int l15 = l & 15, l4 = l >> 4;

  f32x4 acc[4] = {};
  float csacc = 0.f;

  for (int tt = 0; tt < 8; ++tt) {
    const int t0 = tt * 128;
    __syncthreads();
    #pragma unroll
    for (int i = 0; i < 4; ++i) {
      int issue = w * 4 + i;
      int row = issue * 4 + l4;
      int gs  = l15 ^ (row & 15);
      gl_lds16(&S[(size_t)row * TS + t0 + gs * 8], &t_s[issue * 512]);
    }
    __syncthreads();

    {
      int r = w * 16 + l15;
      #pragma unroll
      for (int j = 0; j < 4; ++j) {
        int gg = ((l4 * 4 + j) ^ (r & 15)) * 8;
        uint4 vv = *(const uint4*)&t_s[r * 128 + gg];
        const ushort* pu = (const ushort*)&vv;
        #pragma unroll
        for (int e2 = 0; e2 < 8; ++e2) csacc += bf2f(pu[e2]);
      }
    }

    #pragma unroll
    for (int ks = 0; ks < 4; ++ks) {
      int ar = w * 16 + l15;
      bf16x8 af = *(const bf16x8*)&t_s[ar * 128 + ((ks * 4 + l4) ^ (ar & 15)) * 8];
      #pragma unroll
      for (int ni = 0; ni < 4; ++ni) {
        int br = ni * 16 + l15;
        bf16x8 bf_ = *(const bf16x8*)&t_s[br * 128 + ((ks * 4 + l4) ^ (br & 15)) * 8];
        acc[ni] = MFMA(af, bf_, acc[ni]);
      }
    }
  }

  csacc += __shfl_xor(csacc, 16);
  csacc += __shfl_xor(csacc, 32);
  if (l4 == 0)
    csb[(mat * 32 + z) * 64 + w * 16 + l15] = csacc;

  ushort* G = (mat ? g2b : g1b) + (size_t)z * 4096;
  #pragma unroll
  for (int ni = 0; ni < 4; ++ni)
    #pragma unroll
    for (int e = 0; e < 4; ++e)
      G[(w * 16 + l4 * 4 + e) * 64 + ni * 16 + l15] = f2bf(acc[ni][e]);
}

// ---------------- fused attention v7: V double-buffered, 1 barrier/iter --------
// Block = one head z, one 32-row Q-tile (1024 blocks). Pair p = w>>1 handles kv
// cols [p*32,p*32+32) of the shared 64-kv tile; wr = w&1 is 16-row group.
// No-max softmax => pair contributions additive; Gram-trick stats.
// LDS 53KB -> 3 blocks/CU. Per iter: prefetch K/V(i+1) -> QK^T -> softmax ->
// PV -> ONE barrier. P write->PV read is same-wave (lgkmcnt-ordered).
__global__ __launch_bounds__(256, 3)
void attn_fused(const ushort* __restrict__ qb, const ushort* __restrict__ kb,
                const ushort* __restrict__ q2b, const ushort* __restrict__ k2b,
                const ushort* __restrict__ vtb, ushort* __restrict__ yb,
                const ushort* __restrict__ g1b, const ushort* __restrict__ g2b,
                const float* __restrict__ csb,
                const float* __restrict__ mixture, const float* __restrict__ qsc)
{
  __shared__ ushort kbuf [2][4096];  // K tile [64 kv][64 d] swz g^=kv&7 (buf1: Q2 in prologue)
  __shared__ ushort k2buf[2][4096];  // K2 tile
  __shared__ ushort vbuf [2][4096];  // V tile [64 d][64 kv] swz g^=d&7
  __shared__ ushort p_s  [2 * 32 * 40]; // P per pair [32 r][40] pad (Q in prologue, first 4KB)

  const int idx  = blockIdx.x;
  const int pp   = idx >> 8;                     // 0..3 sweep (big tiles first)
  const int base = idx & 255;
  const int xcd  = base & 7;
  const int mm   = base >> 3;                    // 0..31
  const int qq   = mm & 7;
  const int z    = (mm >> 3) * 8 + xcd;          // head id, affine to XCD
  const int q32  = 31 - (pp * 8 + qq);           // 0..31, big first
  const int b    = z >> 4, h = z & 15;
  const int m0   = q32 * 32;
  const int nkv  = (q32 >> 1) + 1;               // # 64-kv tiles needed (causal)

  const ushort* Q  = qb  + (size_t)b * TS * CS + h * DHEAD;
  const ushort* Q2 = q2b + (size_t)b * TS * CS + h * DHEAD;
  const ushort* K  = kb  + (size_t)b * TS * CS + h * DHEAD;
  const ushort* K2 = k2b + (size_t)b * TS * CS + h * DHEAD;
  const ushort* Vt = vtb + (size_t)z * DHEAD * TS;
  const ushort* G1 = g1b + (size_t)z * 4096;
  const ushort* G2 = g2b + (size_t)z * 4096;
  ushort* Y = yb + (size_t)b * TS * CS + h * DHEAD;

  const int t = threadIdx.x, w = t >> 6, l = t & 63;
  const int l15 = l & 15, l4 = l >> 4;
  const int r8 = l >> 3, g7 = l & 7;
  const int p  = w >> 1, wr = w & 1;
  const int qrow = wr * 16 + l15;                // local q-row 0..31

  const float L2E = 1.44269504f;
  const float gm = 1.f / (1.f + __expf(-mixture[0]));
  const float mq2 = gm * qsc[0] * L2E;
  const float om2 = (1.f - gm) * L2E;

  auto stage_k = [&](int ti, int bs) {
    const int t0 = ti * 64;
    #pragma unroll
    for (int i = 0; i < 2; ++i) {
      int issue = w * 2 + i;
      int row = issue * 8 + r8;                  // kv row 0..63
      int gs  = g7 ^ (row & 7);
      gl_lds16(&K [(size_t)(t0 + row) * CS + gs * 8], &kbuf [bs][issue * 512]);
      gl_lds16(&K2[(size_t)(t0 + row) * CS + gs * 8], &k2buf[bs][issue * 512]);
    }
  };
  auto stage_v = [&](int ti, int bs) {
    const int t0 = ti * 64;
    #pragma unroll
    for (int i = 0; i < 2; ++i) {
      int issue = w * 2 + i;
      int row = issue * 8 + r8;                  // d row 0..63
      int gs  = g7 ^ (row & 7);
      gl_lds16(&Vt[(size_t)row * TS + t0 + gs * 8], &vbuf[bs][issue * 512]);
    }
  };

  // ---- prologue: Q -> p_s (4KB), Q2 -> kbuf[1], K0/K2_0 -> buf0, V0 -> vbuf0 ----
  {
    int row = w * 8 + r8;                        // 0..31
    int gs  = g7 ^ (row & 7);
    gl_lds16(&Q [(size_t)(m0 + row) * CS + gs * 8], &p_s[w * 512]);
    gl_lds16(&Q2[(size_t)(m0 + row) * CS + gs * 8], &kbuf[1][w * 512]);
  }
  stage_k(0, 0);
  stage_v(0, 0);
  __syncthreads();

  // Q fragments (B-operand: 16 rows of this wave over l15, k-slice over l4)
  bf16x8 fq[2], fq2[2];
  #pragma unroll
  for (int ks = 0; ks < 2; ++ks) {
    int gg = ((ks * 4 + l4) ^ (qrow & 7)) * 8;
    fq [ks] = *(const bf16x8*)&p_s[qrow * 64 + gg];
    fq2[ks] = *(const bf16x8*)&kbuf[1][qrow * 64 + gg];
  }

  // U = G @ Q^T (G from global, row-major A-frags); lane: d = ni*16+l4*4+e, col=qrow
  f32x4 U1[4] = {}, U2[4] = {};
  #pragma unroll
  for (int ks = 0; ks < 2; ++ks)
    #pragma unroll
    for (int ni = 0; ni < 4; ++ni) {
      bf16x8 bg = *(const bf16x8*)&G1[(ni * 16 + l15) * 64 + ks * 32 + l4 * 8];
      U1[ni] = MFMA(bg, fq[ks], U1[ni]);
    }
  #pragma unroll
  for (int ks = 0; ks < 2; ++ks)
    #pragma unroll
    for (int ni = 0; ni < 4; ++ni) {
      bf16x8 bg = *(const bf16x8*)&G2[(ni * 16 + l15) * 64 + ks * 32 + l4 * 8];
      U2[ni] = MFMA(bg, fq2[ks], U2[ni]);
    }

  // per-lane stats: ssq = sum_d U[d]*q[d]; mudot = sum_d q[d]*cs[d]
  float ssq1 = 0.f, md1 = 0.f, ssq2 = 0.f, md2 = 0.f;
  #pragma unroll
  for (int ni = 0; ni < 4; ++ni) {
    int gsq = (ni * 2 + (l4 >> 1)) ^ (qrow & 7);
    int off = qrow * 64 + gsq * 8 + (l4 & 1) * 4;
    ushort qa[4], qb2[4];
    *(uint2*)qa  = *(const uint2*)&p_s[off];
    *(uint2*)qb2 = *(const uint2*)&kbuf[1][off];
    float c1[4], c2[4];
    *(float4*)c1 = *(const float4*)&csb[z * 64 + ni * 16 + l4 * 4];
    *(float4*)c2 = *(const float4*)&csb[2048 + z * 64 + ni * 16 + l4 * 4];
    #pragma unroll
    for (int e = 0; e < 4; ++e) {
      float qv1 = bf2f(qa[e]), qv2 = bf2f(qb2[e]);
      ssq1 = fmaf(U1[ni][e], qv1, ssq1); md1 = fmaf(qv1, c1[e], md1);
      ssq2 = fmaf(U2[ni][e], qv2, ssq2); md2 = fmaf(qv2, c2[e], md2);
    }
  }
  ssq1 += __shfl_xor(ssq1, 16); md1 += __shfl_xor(md1, 16);
  ssq2 += __shfl_xor(ssq2, 16); md2 += __shfl_xor(md2, 16);
  ssq1 += __shfl_xor(ssq1, 32); md1 += __shfl_xor(md1, 32);
  ssq2 += __shfl_xor(ssq2, 32); md2 += __shfl_xor(md2, 32);

  const float mu1 = md1 * (1.f / TS), mu2 = md2 * (1.f / TS);
  const float va1 = (ssq1 - (float)TS * mu1 * mu1) * (1.f / (TS - 1));
  const float va2 = (ssq2 - (float)TS * mu2 * mu2) * (1.f / (TS - 1));
  const float iv1 = 1.f / (sqrtf(fmaxf(va1, 0.f)) + EPSV);
  const float iv2 = 1.f / (sqrtf(fmaxf(va2, 0.f)) + EPSV);
  __syncthreads();                   // release p_s (Q) + kbuf[1] (Q2)

  // ---- kv loop: prefetch K/V(i+1) -> QK^T -> softmax -> PV -> ONE barrier ----
  float lrow = 0.f;
  f32x4 accO[4] = {};                // lane: row = wr*16 + l4*4+e, d = ni*16+l15

  for (int i = 0; i < nkv; ++i) {
    const int t0  = i * 64;
    const int cur = i & 1;
    if (i + 1 < nkv) { stage_k(i + 1, cur ^ 1); stage_v(i + 1, cur ^ 1); }

    const ushort* ks_ = kbuf [cur];
    const ushort* k2s_= k2buf[cur];

    // QK^T swapped: A = K rows (pair half), B = Q rows; kv = p*32+ni*16+l4*4+e
    f32x4 a1[2] = {}, a2[2] = {};
    #pragma unroll
    for (int ks = 0; ks < 2; ++ks) {
      bf16x8 bk[2], bk2[2];
      #pragma unroll
      for (int ni = 0; ni < 2; ++ni) {
        int j  = p * 32 + ni * 16 + l15;
        int gg = ((ks * 4 + l4) ^ (j & 7)) * 8;
        bk [ni] = *(const bf16x8*)&ks_ [j * 64 + gg];
        bk2[ni] = *(const bf16x8*)&k2s_[j * 64 + gg];
      }
      #pragma unroll
      for (int ni = 0; ni < 2; ++ni) {
        a1[ni] = MFMA(bk [ni], fq [ks], a1[ni]);
        a2[ni] = MFMA(bk2[ni], fq2[ks], a2[ni]);
      }
    }

    // normalize + gate + causal mask + exp2; pack & store P (pair-local rows)
    const int grow = m0 + qrow;
    #pragma unroll
    for (int ni = 0; ni < 2; ++ni) {
      float pe[4];
      #pragma unroll
      for (int e = 0; e < 4; ++e) {
        float n1 = (a1[ni][e] - mu1) * iv1;
        float n2 = (a2[ni][e] - mu2) * iv2;
        float sc = n1 * fmaf(mq2, n2, om2);
        float pv = exp2f(sc);
        int gcol = t0 + p * 32 + ni * 16 + l4 * 4 + e;
        pv = (gcol <= grow) ? pv : 0.f;
        lrow += pv;
        pe[e] = pv;
      }
      uint32_t pk01, pk23;
      asm("v_cvt_pk_bf16_f32 %0, %1, %2" : "=v"(pk01) : "v"(pe[0]), "v"(pe[1]));
      asm("v_cvt_pk_bf16_f32 %0, %1, %2" : "=v"(pk23) : "v"(pe[2]), "v"(pe[3]));
      uint2 pk; pk.x = pk01; pk.y = pk23;
      *(uint2*)&p_s[p * 1280 + qrow * 40 + ni * 16 + l4 * 4] = pk;
    }

    // PV: A = P[own rows][pair kv-half], B = V[d][pair kv-half]; same-wave LDS dep
    {
      bf16x8 ap = *(const bf16x8*)&p_s[p * 1280 + qrow * 40 + l4 * 8];
      #pragma unroll
      for (int ni = 0; ni < 4; ++ni) {
        int d  = ni * 16 + l15;
        int gg = ((p * 4 + l4) ^ (d & 7)) * 8;
        bf16x8 bv = *(const bf16x8*)&vbuf[cur][d * 64 + gg];
        accO[ni] = MFMA(ap, bv, accO[ni]);
      }
    }

    __syncthreads();   // drains prefetches + releases cur buffers
  }

  // ---- epilogue: combine wave pairs (additive, no-max), normalize, write ----
  lrow += __shfl_xor(lrow, 16);
  lrow += __shfl_xor(lrow, 32);      // row-sum of this pair's kv half

  float* fb = (float*)kbuf;          // [32][64] f32 partial O (8KB of 16KB)
  float* fl = (float*)k2buf;         // [32] f32 partial lrow
  if (p == 1) {
    #pragma unroll
    for (int ni = 0; ni < 4; ++ni)
      #pragma unroll
      for (int e = 0; e < 4; ++e)
        fb[(wr * 16 + l4 * 4 + e) * 64 + ni * 16 + l15] = accO[ni][e];
    if (l4 == 0) fl[qrow] = lrow;
  }
  __syncthreads();
  if (p == 0) {
    float lt = lrow + fl[qrow];      // total row denom (lane l15-indexed)
    float il[4];
    #pragma unroll
    for (int e = 0; e < 4; ++e)
      il[e] = 1.f / __shfl(lt, l4 * 4 + e);
    #pragma unroll
    for (int ni = 0; ni < 4; ++ni)
      #pragma unroll
      for (int e = 0; e < 4; ++e) {
        float o = accO[ni][e] + fb[(wr * 16 + l4 * 4 + e) * 64 + ni * 16 + l15];
        Y[(size_t)(m0 + wr * 16 + l4 * 4 + e) * CS + ni * 16 + l15] = f2bf(o * il[e]);
      }
  }
}

// ---------------- launcher ----------------
extern "C" void kernel_launch(void* const* d_in, const int* in_sizes, int n_in,
                              void* d_out, int out_size, void* d_ws, size_t ws_size,
                              hipStream_t stream) {
  const float* x    = (const float*)d_in[0];
  const float* Wq   = (const float*)d_in[1];
  const float* Wk   = (const float*)d_in[2];
  const float* Wv   = (const float*)d_in[3];
  const float* Wq2  = (const float*)d_in[4];
  const float* Wk2  = (const float*)d_in[5];
  const float* Wo   = (const float*)d_in[6];
  const float* mixture = (const float*)d_in[7];
  const float* qsc  = (const float*)d_in[8];
  float* out = (float*)d_out;

  const size_t MT = (size_t)NBATCH * TS;   // 2048
  ushort* ws = (ushort*)d_ws;
  ushort* xb   = ws;                                  // 2M
  ushort* wcat = xb   + (size_t)2 * MEG;              // 6M: wq,wk,wq2,wk2,wv,wo
  ushort* qb   = wcat + (size_t)6 * MEG;              // 2M (pre-scaled by 1/8)
  ushort* q2b  = qb   + (size_t)2 * MEG;              // 2M (pre-scaled by 1/8)
  ushort* kb   = q2b  + (size_t)2 * MEG;              // 2M
  ushort* k2b  = kb   + (size_t)2 * MEG;              // 2M
  ushort* vtb  = k2b  + (size_t)2 * MEG;              // 2M  [B*NH][64][T]
  ushort* yb   = vtb  + (size_t)2 * MEG;              // 2M
  ushort* ktb  = yb   + (size_t)2 * MEG;              // 2M  [B*NH][64][T]
  ushort* k2tb = ktb  + (size_t)2 * MEG;              // 2M
  ushort* g1b  = k2tb + (size_t)2 * MEG;              // 128K: [32][64][64] bf16
  ushort* g2b  = g1b  + (size_t)(MEG / 8);            // 128K
  float*  csb  = (float*)(g2b + (size_t)(MEG / 8));   // [2][32][64] fp32
  ushort* wob  = wcat + (size_t)5 * MEG;

  // 1. cast everything to bf16
  cast_all<<<2048, 256, 0, stream>>>(x, Wq, Wk, Wv, Wq2, Wk2, Wo, xb, wcat);

  // 2. fused projections (+ transposed K, K2 for gram), BM=128/BK=64 dbuf-prefetch
  gemm_proj<<<dim3(5 * CS / BN, MT / BM, 1), 256, 0, stream>>>(
      xb, wcat, qb, kb, q2b, k2b, vtb, ktb, k2tb);

  // 3. Gram matrices + colsums
  gram<<<64, 256, 0, stream>>>(ktb, k2tb, g1b, g2b, csb);

  // 4. fused attention (1024 blocks, 3/CU, V dbuf, 1 barrier/iter)
  attn_fused<<<1024, 256, 0, stream>>>(qb, kb, q2b, k2b, vtb, yb,
                                       g1b, g2b, csb, mixture, qsc);

  // 5. output projection (fp32 out), 512 blocks, dbuf-prefetch
  gemm_out<<<512, 256, 0, stream>>>(yb, wob, out);
}

// Round 12
// 109.618 us; speedup vs baseline: 1.0532x; 1.0532x over previous
//
#include <hip/hip_runtime.h>
#include <hip/hip_bf16.h>
#include <stdint.h>

#define TS 1024   // T
#define CS 1024   // C
#define NH 16
#define DHEAD 64
#define NBATCH 2
#define EPSV 1e-5f
#define MEG 1048576

typedef __bf16 bf16x8 __attribute__((ext_vector_type(8)));
typedef float  f32x4  __attribute__((ext_vector_type(4)));

#define MFMA(a, b, c) __builtin_amdgcn_mfma_f32_16x16x32_bf16((a), (b), (c), 0, 0, 0)

__device__ __forceinline__ float bf2f(ushort u){
  union { uint32_t i; float f; } v; v.i = ((uint32_t)u) << 16; return v.f;
}
__device__ __forceinline__ ushort f2bf(float f){
  union { float f; uint32_t i; } v; v.f = f;
  uint32_t r = v.i + 0x7FFFu + ((v.i >> 16) & 1u);
  return (ushort)(r >> 16);
}

// async global->LDS, 16B per lane. LDS dest wave-uniform base + lane*16B (linear);
// global src per-lane (enables pre-swizzled-source LDS layouts).
__device__ __forceinline__ void gl_lds16(const ushort* g, ushort* l) {
  __builtin_amdgcn_global_load_lds(
      (const __attribute__((address_space(1))) void*)g,
      (__attribute__((address_space(3))) void*)l, 16, 0, 0);
}

// ---------------- fused cast fp32 -> bf16 of all 7 tensors ----------------
__global__ __launch_bounds__(256)
void cast_all(const float* __restrict__ x,
              const float* __restrict__ Wq, const float* __restrict__ Wk,
              const float* __restrict__ Wv, const float* __restrict__ Wq2,
              const float* __restrict__ Wk2, const float* __restrict__ Wo,
              ushort* __restrict__ xb, ushort* __restrict__ wcat)
{
  const int XC = 524288, TOT = 2097152;
  for (int idx = blockIdx.x * 256 + threadIdx.x; idx < TOT; idx += 524288) {
    const float* s; ushort* d; int c;
    if (idx < XC) { s = x; d = xb; c = idx; }
    else {
      int r = idx - XC; int w = r >> 18; c = r & 262143;
      switch (w) {
        case 0:  s = Wq;  d = wcat;           break;
        case 1:  s = Wk;  d = wcat + 1*MEG;   break;
        case 2:  s = Wv;  d = wcat + 4*MEG;   break;
        case 3:  s = Wq2; d = wcat + 2*MEG;   break;
        case 4:  s = Wk2; d = wcat + 3*MEG;   break;
        default: s = Wo;  d = wcat + 5*MEG;   break;
      }
    }
    float4 v = *(const float4*)(s + (size_t)c * 4);
    ushort4 o; o.x = f2bf(v.x); o.y = f2bf(v.y); o.z = f2bf(v.z); o.w = f2bf(v.w);
    *(ushort4*)(d + (size_t)c * 4) = o;
  }
}

#define BN 128

// ---------------- fused projection GEMM: [x]@[Wq;Wk;Wq2;Wk2;Wv]^T ----------------
// v3 (reverted from dbuf regression): BM=64 x BN=128, BK=64, single-buffered
// (24KB LDS -> ~5 blocks/CU TLP hides the barrier drain; explicit dbuf at 64KB
// measured WORSE: 40.5 -> 46.8 us, occupancy cliff). 1D grid 1280, XCD-swizzled.
__global__ __launch_bounds__(256, 2)
void gemm_proj(const ushort* __restrict__ A, const ushort* __restrict__ Bt,
               ushort* __restrict__ qb, ushort* __restrict__ kb,
               ushort* __restrict__ q2b, ushort* __restrict__ k2b,
               ushort* __restrict__ vtb,
               ushort* __restrict__ ktb, ushort* __restrict__ k2tb)
{
  __shared__ ushort a_s[64 * 64];    // [64 rows][64 cols] swz g^=row&7 (8KB)
  __shared__ ushort b_s[128 * 64];   // 16KB

  const int bid = blockIdx.x;
  const int s   = (bid & 7) * 160 + (bid >> 3);   // bijective, 1280%8==0
  const int n0  = (s >> 5) * BN;                  // x in [5c, 5c+5) per XCD c
  const int m0  = (s & 31) * 64;

  const int t  = threadIdx.x;
  const int w  = t >> 6, l = t & 63;
  const int wr = w >> 1, wc = w & 1;
  const int l15 = l & 15, l4 = l >> 4;
  const int r8 = l >> 3, g7 = l & 7;

  f32x4 acc[2][4] = {};

  for (int k0 = 0; k0 < CS; k0 += 64) {
    #pragma unroll
    for (int i = 0; i < 2; ++i) {
      int issue = w * 2 + i;              // 0..7
      int row   = issue * 8 + r8;         // 0..63
      int gs    = g7 ^ (row & 7);
      gl_lds16(&A[(size_t)(m0 + row) * CS + k0 + gs * 8], &a_s[issue * 512]);
    }
    #pragma unroll
    for (int i = 0; i < 4; ++i) {
      int issue = w * 4 + i;              // 0..15
      int row   = issue * 8 + r8;         // 0..127
      int gs    = g7 ^ (row & 7);
      gl_lds16(&Bt[(size_t)(n0 + row) * CS + k0 + gs * 8], &b_s[issue * 512]);
    }
    __syncthreads();

    #pragma unroll
    for (int ks = 0; ks < 2; ++ks) {
      bf16x8 af[2], bfr[4];
      #pragma unroll
      for (int mi = 0; mi < 2; ++mi) {
        int row = wr * 32 + mi * 16 + l15;
        int gl  = (ks * 4 + l4) ^ (row & 7);
        af[mi] = *(const bf16x8*)&a_s[row * 64 + gl * 8];
      }
      #pragma unroll
      for (int ni = 0; ni < 4; ++ni) {
        int row = wc * 64 + ni * 16 + l15;
        int gl  = (ks * 4 + l4) ^ (row & 7);
        bfr[ni] = *(const bf16x8*)&b_s[row * 64 + gl * 8];
      }
      #pragma unroll
      for (int mi = 0; mi < 2; ++mi)
        #pragma unroll
        for (int ni = 0; ni < 4; ++ni)
          acc[mi][ni] = MFMA(af[mi], bfr[ni], acc[mi][ni]);
    }

    __syncthreads();
  }

  #pragma unroll
  for (int mi = 0; mi < 2; ++mi) {
    #pragma unroll
    for (int ni = 0; ni < 4; ++ni) {
      int col  = n0 + wc * 64 + ni * 16 + l15;
      int row0 = m0 + wr * 32 + mi * 16 + l4 * 4;
      int seg  = col >> 10, cc = col & (CS - 1);
      if (seg < 4) {
        ushort* dst = (seg == 0) ? qb : (seg == 1) ? kb : (seg == 2) ? q2b : k2b;
        float sc = (seg & 1) ? 1.f : 0.125f;   // fold 1/sqrt(Dh) into q, q2
        #pragma unroll
        for (int e = 0; e < 4; ++e)
          dst[(size_t)(row0 + e) * CS + cc] = f2bf(acc[mi][ni][e] * sc);
        if (seg == 1 || seg == 3) {
          int bb = row0 >> 10, tt = row0 & (TS - 1);
          int hh = cc >> 6, dd = cc & (DHEAD - 1);
          ushort* td = (seg == 1) ? ktb : k2tb;
          ushort4 o;
          o.x = f2bf(acc[mi][ni][0]); o.y = f2bf(acc[mi][ni][1]);
          o.z = f2bf(acc[mi][ni][2]); o.w = f2bf(acc[mi][ni][3]);
          *(ushort4*)&td[(((size_t)(bb * NH + hh) * DHEAD + dd) * TS) + tt] = o;
        }
      } else {
        int bb = row0 >> 10, tt = row0 & (TS - 1);
        int hh = cc >> 6, dd = cc & (DHEAD - 1);
        ushort4 o;
        o.x = f2bf(acc[mi][ni][0]); o.y = f2bf(acc[mi][ni][1]);
        o.z = f2bf(acc[mi][ni][2]); o.w = f2bf(acc[mi][ni][3]);
        *(ushort4*)&vtb[(((size_t)(bb * NH + hh) * DHEAD + dd) * TS) + tt] = o;
      }
    }
  }
}

// ---------------- out-projection GEMM: out = y @ Wo^T (fp32 out) --------------
// v2 (reverted): BM=64 x BN=64, BK=32, single-buffered, grid 512 (2 blocks/CU),
// 1D XCD-swizzled.
__global__ __launch_bounds__(256, 2)
void gemm_out(const ushort* __restrict__ A, const ushort* __restrict__ Bt,
              float* __restrict__ C)
{
  __shared__ ushort a_s[64 * 32];
  __shared__ ushort b_s[64 * 32];

  const int bid = blockIdx.x;
  const int s   = (bid & 7) * 64 + (bid >> 3);    // bijective, 512%8==0
  const int n0  = (s >> 5) * 64;
  const int m0  = (s & 31) * 64;

  const int t  = threadIdx.x;
  const int w  = t >> 6, l = t & 63;
  const int wr = w >> 1, wc = w & 1;
  const int l15 = l & 15, l4 = l >> 4;
  const int rs = l >> 2;
  const int c8 = (l & 3) * 8;

  f32x4 acc[2][2] = {};

  for (int k0 = 0; k0 < CS; k0 += 32) {
    gl_lds16(&A [(size_t)(m0 + w * 16 + rs) * CS + k0 + c8], &a_s[w * 512]);
    gl_lds16(&Bt[(size_t)(n0 + w * 16 + rs) * CS + k0 + c8], &b_s[w * 512]);
    __syncthreads();

    bf16x8 af[2], bfr[2];
    #pragma unroll
    for (int mi = 0; mi < 2; ++mi)
      af[mi] = *(const bf16x8*)&a_s[(wr * 32 + mi * 16 + l15) * 32 + l4 * 8];
    #pragma unroll
    for (int ni = 0; ni < 2; ++ni)
      bfr[ni] = *(const bf16x8*)&b_s[(wc * 32 + ni * 16 + l15) * 32 + l4 * 8];

    #pragma unroll
    for (int mi = 0; mi < 2; ++mi)
      #pragma unroll
      for (int ni = 0; ni < 2; ++ni)
        acc[mi][ni] = MFMA(af[mi], bfr[ni], acc[mi][ni]);

    __syncthreads();
  }

  #pragma unroll
  for (int mi = 0; mi < 2; ++mi)
    #pragma unroll
    for (int ni = 0; ni < 2; ++ni)
      #pragma unroll
      for (int e = 0; e < 4; ++e)
        C[(size_t)(m0 + wr * 32 + mi * 16 + l4 * 4 + e) * CS +
          n0 + wc * 32 + ni * 16 + l15] = acc[mi][ni][e];
}

// ---------------- Gram kernel: G = K^T K (64x64, bf16 out) + colsum(K) ----------
__global__ __launch_bounds__(256, 2)
void gram(const ushort* __restrict__ ktb, const ushort* __restrict__ k2tb,
          ushort* __restrict__ g1b, ushort* __restrict__ g2b,
          float* __restrict__ csb)
{
  __shared__ ushort t_s[64 * 128];   // [64 d][128 t], granule-swizzled g ^= d&15

  const int mat = blockIdx.x & 1, z = blockIdx.x >> 1;
  const ushort* S = (mat ? k2tb : ktb) + (size_t)z * DHEAD * TS;

  const int t = threadIdx.x, w = t >> 6, l = t & 63;
  const int l15 = l & 15, l4 = l >> 4;

  f32x4 acc[4] = {};
  float csacc = 0.f;

  for (int tt = 0; tt < 8; ++tt) {
    const int t0 = tt * 128;
    __syncthreads();
    #pragma unroll
    for (int i = 0; i < 4; ++i) {
      int issue = w * 4 + i;
      int row = issue * 4 + l4;
      int gs  = l15 ^ (row & 15);
      gl_lds16(&S[(size_t)row * TS + t0 + gs * 8], &t_s[issue * 512]);
    }
    __syncthreads();

    {
      int r = w * 16 + l15;
      #pragma unroll
      for (int j = 0; j < 4; ++j) {
        int gg = ((l4 * 4 + j) ^ (r & 15)) * 8;
        uint4 vv = *(const uint4*)&t_s[r * 128 + gg];
        const ushort* pu = (const ushort*)&vv;
        #pragma unroll
        for (int e2 = 0; e2 < 8; ++e2) csacc += bf2f(pu[e2]);
      }
    }

    #pragma unroll
    for (int ks = 0; ks < 4; ++ks) {
      int ar = w * 16 + l15;
      bf16x8 af = *(const bf16x8*)&t_s[ar * 128 + ((ks * 4 + l4) ^ (ar & 15)) * 8];
      #pragma unroll
      for (int ni = 0; ni < 4; ++ni) {
        int br = ni * 16 + l15;
        bf16x8 bf_ = *(const bf16x8*)&t_s[br * 128 + ((ks * 4 + l4) ^ (br & 15)) * 8];
        acc[ni] = MFMA(af, bf_, acc[ni]);
      }
    }
  }

  csacc += __shfl_xor(csacc, 16);
  csacc += __shfl_xor(csacc, 32);
  if (l4 == 0)
    csb[(mat * 32 + z) * 64 + w * 16 + l15] = csacc;

  ushort* G = (mat ? g2b : g1b) + (size_t)z * 4096;
  #pragma unroll
  for (int ni = 0; ni < 4; ++ni)
    #pragma unroll
    for (int e = 0; e < 4; ++e)
      G[(w * 16 + l4 * 4 + e) * 64 + ni * 16 + l15] = f2bf(acc[ni][e]);
}

// ---------------- fused attention v8: balanced sweeps + setprio ----------------
// Block = one head z, one 32-row Q-tile (1024 blocks). Pair p = w>>1 handles kv
// cols [p*32,p*32+32) of the shared 64-kv tile; wr = w&1 is 16-row group.
// No-max softmax => pair contributions additive; Gram-trick stats.
// LDS 53KB -> 3 blocks/CU. Per iter: prefetch K/V(i+1) -> QK^T -> softmax ->
// PV -> ONE barrier. v8: per-CU sweep q32 set {31-qq, qq, 23-qq, 8+qq} sums to
// ~35 iters for EVERY qq (old mapping: 28..42, 30% tail); s_setprio(1) around
// MFMA clusters (T5: +4-7% on phase-diverse attn, m191).
__global__ __launch_bounds__(256, 3)
void attn_fused(const ushort* __restrict__ qb, const ushort* __restrict__ kb,
                const ushort* __restrict__ q2b, const ushort* __restrict__ k2b,
                const ushort* __restrict__ vtb, ushort* __restrict__ yb,
                const ushort* __restrict__ g1b, const ushort* __restrict__ g2b,
                const float* __restrict__ csb,
                const float* __restrict__ mixture, const float* __restrict__ qsc)
{
  __shared__ ushort kbuf [2][4096];  // K tile [64 kv][64 d] swz g^=kv&7 (buf1: Q2 in prologue)
  __shared__ ushort k2buf[2][4096];  // K2 tile
  __shared__ ushort vbuf [2][4096];  // V tile [64 d][64 kv] swz g^=d&7
  __shared__ ushort p_s  [2 * 32 * 40]; // P per pair [32 r][40] pad (Q in prologue, first 4KB)

  const int idx  = blockIdx.x;
  const int pp   = idx >> 8;                     // 0..3 sweep (big tiles first)
  const int base = idx & 255;
  const int xcd  = base & 7;
  const int mm   = base >> 3;                    // 0..31
  const int qq   = mm & 7;
  const int z    = (mm >> 3) * 8 + xcd;          // head id, affine to XCD
  // balanced sweeps: per-CU (fixed qq) totals ~35 iters for every qq
  const int q32  = (pp == 0) ? (31 - qq) : (pp == 1) ? qq
                 : (pp == 2) ? (23 - qq) : (8 + qq);
  const int b    = z >> 4, h = z & 15;
  const int m0   = q32 * 32;
  const int nkv  = (q32 >> 1) + 1;               // # 64-kv tiles needed (causal)

  const ushort* Q  = qb  + (size_t)b * TS * CS + h * DHEAD;
  const ushort* Q2 = q2b + (size_t)b * TS * CS + h * DHEAD;
  const ushort* K  = kb  + (size_t)b * TS * CS + h * DHEAD;
  const ushort* K2 = k2b + (size_t)b * TS * CS + h * DHEAD;
  const ushort* Vt = vtb + (size_t)z * DHEAD * TS;
  const ushort* G1 = g1b + (size_t)z * 4096;
  const ushort* G2 = g2b + (size_t)z * 4096;
  ushort* Y = yb + (size_t)b * TS * CS + h * DHEAD;

  const int t = threadIdx.x, w = t >> 6, l = t & 63;
  const int l15 = l & 15, l4 = l >> 4;
  const int r8 = l >> 3, g7 = l & 7;
  const int p  = w >> 1, wr = w & 1;
  const int qrow = wr * 16 + l15;                // local q-row 0..31

  const float L2E = 1.44269504f;
  const float gm = 1.f / (1.f + __expf(-mixture[0]));
  const float mq2 = gm * qsc[0] * L2E;
  const float om2 = (1.f - gm) * L2E;

  auto stage_k = [&](int ti, int bs) {
    const int t0 = ti * 64;
    #pragma unroll
    for (int i = 0; i < 2; ++i) {
      int issue = w * 2 + i;
      int row = issue * 8 + r8;                  // kv row 0..63
      int gs  = g7 ^ (row & 7);
      gl_lds16(&K [(size_t)(t0 + row) * CS + gs * 8], &kbuf [bs][issue * 512]);
      gl_lds16(&K2[(size_t)(t0 + row) * CS + gs * 8], &k2buf[bs][issue * 512]);
    }
  };
  auto stage_v = [&](int ti, int bs) {
    const int t0 = ti * 64;
    #pragma unroll
    for (int i = 0; i < 2; ++i) {
      int issue = w * 2 + i;
      int row = issue * 8 + r8;                  // d row 0..63
      int gs  = g7 ^ (row & 7);
      gl_lds16(&Vt[(size_t)row * TS + t0 + gs * 8], &vbuf[bs][issue * 512]);
    }
  };

  // ---- prologue: Q -> p_s (4KB), Q2 -> kbuf[1], K0/K2_0 -> buf0, V0 -> vbuf0 ----
  {
    int row = w * 8 + r8;                        // 0..31
    int gs  = g7 ^ (row & 7);
    gl_lds16(&Q [(size_t)(m0 + row) * CS + gs * 8], &p_s[w * 512]);
    gl_lds16(&Q2[(size_t)(m0 + row) * CS + gs * 8], &kbuf[1][w * 512]);
  }
  stage_k(0, 0);
  stage_v(0, 0);
  __syncthreads();

  // Q fragments (B-operand: 16 rows of this wave over l15, k-slice over l4)
  bf16x8 fq[2], fq2[2];
  #pragma unroll
  for (int ks = 0; ks < 2; ++ks) {
    int gg = ((ks * 4 + l4) ^ (qrow & 7)) * 8;
    fq [ks] = *(const bf16x8*)&p_s[qrow * 64 + gg];
    fq2[ks] = *(const bf16x8*)&kbuf[1][qrow * 64 + gg];
  }

  // U = G @ Q^T (G from global, row-major A-frags); lane: d = ni*16+l4*4+e, col=qrow
  f32x4 U1[4] = {}, U2[4] = {};
  #pragma unroll
  for (int ks = 0; ks < 2; ++ks)
    #pragma unroll
    for (int ni = 0; ni < 4; ++ni) {
      bf16x8 bg = *(const bf16x8*)&G1[(ni * 16 + l15) * 64 + ks * 32 + l4 * 8];
      U1[ni] = MFMA(bg, fq[ks], U1[ni]);
    }
  #pragma unroll
  for (int ks = 0; ks < 2; ++ks)
    #pragma unroll
    for (int ni = 0; ni < 4; ++ni) {
      bf16x8 bg = *(const bf16x8*)&G2[(ni * 16 + l15) * 64 + ks * 32 + l4 * 8];
      U2[ni] = MFMA(bg, fq2[ks], U2[ni]);
    }

  // per-lane stats: ssq = sum_d U[d]*q[d]; mudot = sum_d q[d]*cs[d]
  float ssq1 = 0.f, md1 = 0.f, ssq2 = 0.f, md2 = 0.f;
  #pragma unroll
  for (int ni = 0; ni < 4; ++ni) {
    int gsq = (ni * 2 + (l4 >> 1)) ^ (qrow & 7);
    int off = qrow * 64 + gsq * 8 + (l4 & 1) * 4;
    ushort qa[4], qb2[4];
    *(uint2*)qa  = *(const uint2*)&p_s[off];
    *(uint2*)qb2 = *(const uint2*)&kbuf[1][off];
    float c1[4], c2[4];
    *(float4*)c1 = *(const float4*)&csb[z * 64 + ni * 16 + l4 * 4];
    *(float4*)c2 = *(const float4*)&csb[2048 + z * 64 + ni * 16 + l4 * 4];
    #pragma unroll
    for (int e = 0; e < 4; ++e) {
      float qv1 = bf2f(qa[e]), qv2 = bf2f(qb2[e]);
      ssq1 = fmaf(U1[ni][e], qv1, ssq1); md1 = fmaf(qv1, c1[e], md1);
      ssq2 = fmaf(U2[ni][e], qv2, ssq2); md2 = fmaf(qv2, c2[e], md2);
    }
  }
  ssq1 += __shfl_xor(ssq1, 16); md1 += __shfl_xor(md1, 16);
  ssq2 += __shfl_xor(ssq2, 16); md2 += __shfl_xor(md2, 16);
  ssq1 += __shfl_xor(ssq1, 32); md1 += __shfl_xor(md1, 32);
  ssq2 += __shfl_xor(ssq2, 32); md2 += __shfl_xor(md2, 32);

  const float mu1 = md1 * (1.f / TS), mu2 = md2 * (1.f / TS);
  const float va1 = (ssq1 - (float)TS * mu1 * mu1) * (1.f / (TS - 1));
  const float va2 = (ssq2 - (float)TS * mu2 * mu2) * (1.f / (TS - 1));
  const float iv1 = 1.f / (sqrtf(fmaxf(va1, 0.f)) + EPSV);
  const float iv2 = 1.f / (sqrtf(fmaxf(va2, 0.f)) + EPSV);
  __syncthreads();                   // release p_s (Q) + kbuf[1] (Q2)

  // ---- kv loop: prefetch K/V(i+1) -> QK^T -> softmax -> PV -> ONE barrier ----
  float lrow = 0.f;
  f32x4 accO[4] = {};                // lane: row = wr*16 + l4*4+e, d = ni*16+l15

  for (int i = 0; i < nkv; ++i) {
    const int t0  = i * 64;
    const int cur = i & 1;
    if (i + 1 < nkv) { stage_k(i + 1, cur ^ 1); stage_v(i + 1, cur ^ 1); }

    const ushort* ks_ = kbuf [cur];
    const ushort* k2s_= k2buf[cur];

    // QK^T swapped: A = K rows (pair half), B = Q rows; kv = p*32+ni*16+l4*4+e
    f32x4 a1[2] = {}, a2[2] = {};
    __builtin_amdgcn_s_setprio(1);
    #pragma unroll
    for (int ks = 0; ks < 2; ++ks) {
      bf16x8 bk[2], bk2[2];
      #pragma unroll
      for (int ni = 0; ni < 2; ++ni) {
        int j  = p * 32 + ni * 16 + l15;
        int gg = ((ks * 4 + l4) ^ (j & 7)) * 8;
        bk [ni] = *(const bf16x8*)&ks_ [j * 64 + gg];
        bk2[ni] = *(const bf16x8*)&k2s_[j * 64 + gg];
      }
      #pragma unroll
      for (int ni = 0; ni < 2; ++ni) {
        a1[ni] = MFMA(bk [ni], fq [ks], a1[ni]);
        a2[ni] = MFMA(bk2[ni], fq2[ks], a2[ni]);
      }
    }
    __builtin_amdgcn_s_setprio(0);

    // normalize + gate + causal mask + exp2; pack & store P (pair-local rows)
    const int grow = m0 + qrow;
    #pragma unroll
    for (int ni = 0; ni < 2; ++ni) {
      float pe[4];
      #pragma unroll
      for (int e = 0; e < 4; ++e) {
        float n1 = (a1[ni][e] - mu1) * iv1;
        float n2 = (a2[ni][e] - mu2) * iv2;
        float sc = n1 * fmaf(mq2, n2, om2);
        float pv = exp2f(sc);
        int gcol = t0 + p * 32 + ni * 16 + l4 * 4 + e;
        pv = (gcol <= grow) ? pv : 0.f;
        lrow += pv;
        pe[e] = pv;
      }
      uint32_t pk01, pk23;
      asm("v_cvt_pk_bf16_f32 %0, %1, %2" : "=v"(pk01) : "v"(pe[0]), "v"(pe[1]));
      asm("v_cvt_pk_bf16_f32 %0, %1, %2" : "=v"(pk23) : "v"(pe[2]), "v"(pe[3]));
      uint2 pk; pk.x = pk01; pk.y = pk23;
      *(uint2*)&p_s[p * 1280 + qrow * 40 + ni * 16 + l4 * 4] = pk;
    }

    // PV: A = P[own rows][pair kv-half], B = V[d][pair kv-half]; same-wave LDS dep
    {
      bf16x8 ap = *(const bf16x8*)&p_s[p * 1280 + qrow * 40 + l4 * 8];
      __builtin_amdgcn_s_setprio(1);
      #pragma unroll
      for (int ni = 0; ni < 4; ++ni) {
        int d  = ni * 16 + l15;
        int gg = ((p * 4 + l4) ^ (d & 7)) * 8;
        bf16x8 bv = *(const bf16x8*)&vbuf[cur][d * 64 + gg];
        accO[ni] = MFMA(ap, bv, accO[ni]);
      }
      __builtin_amdgcn_s_setprio(0);
    }

    __syncthreads();   // drains prefetches + releases cur buffers
  }

  // ---- epilogue: combine wave pairs (additive, no-max), normalize, write ----
  lrow += __shfl_xor(lrow, 16);
  lrow += __shfl_xor(lrow, 32);      // row-sum of this pair's kv half

  float* fb = (float*)kbuf;          // [32][64] f32 partial O (8KB of 16KB)
  float* fl = (float*)k2buf;         // [32] f32 partial lrow
  if (p == 1) {
    #pragma unroll
    for (int ni = 0; ni < 4; ++ni)
      #pragma unroll
      for (int e = 0; e < 4; ++e)
        fb[(wr * 16 + l4 * 4 + e) * 64 + ni * 16 + l15] = accO[ni][e];
    if (l4 == 0) fl[qrow] = lrow;
  }
  __syncthreads();
  if (p == 0) {
    float lt = lrow + fl[qrow];      // total row denom (lane l15-indexed)
    float il[4];
    #pragma unroll
    for (int e = 0; e < 4; ++e)
      il[e] = 1.f / __shfl(lt, l4 * 4 + e);
    #pragma unroll
    for (int ni = 0; ni < 4; ++ni)
      #pragma unroll
      for (int e = 0; e < 4; ++e) {
        float o = accO[ni][e] + fb[(wr * 16 + l4 * 4 + e) * 64 + ni * 16 + l15];
        Y[(size_t)(m0 + wr * 16 + l4 * 4 + e) * CS + ni * 16 + l15] = f2bf(o * il[e]);
      }
  }
}

// ---------------- launcher ----------------
extern "C" void kernel_launch(void* const* d_in, const int* in_sizes, int n_in,
                              void* d_out, int out_size, void* d_ws, size_t ws_size,
                              hipStream_t stream) {
  const float* x    = (const float*)d_in[0];
  const float* Wq   = (const float*)d_in[1];
  const float* Wk   = (const float*)d_in[2];
  const float* Wv   = (const float*)d_in[3];
  const float* Wq2  = (const float*)d_in[4];
  const float* Wk2  = (const float*)d_in[5];
  const float* Wo   = (const float*)d_in[6];
  const float* mixture = (const float*)d_in[7];
  const float* qsc  = (const float*)d_in[8];
  float* out = (float*)d_out;

  ushort* ws = (ushort*)d_ws;
  ushort* xb   = ws;                                  // 2M
  ushort* wcat = xb   + (size_t)2 * MEG;              // 6M: wq,wk,wq2,wk2,wv,wo
  ushort* qb   = wcat + (size_t)6 * MEG;              // 2M (pre-scaled by 1/8)
  ushort* q2b  = qb   + (size_t)2 * MEG;              // 2M (pre-scaled by 1/8)
  ushort* kb   = q2b  + (size_t)2 * MEG;              // 2M
  ushort* k2b  = kb   + (size_t)2 * MEG;              // 2M
  ushort* vtb  = k2b  + (size_t)2 * MEG;              // 2M  [B*NH][64][T]
  ushort* yb   = vtb  + (size_t)2 * MEG;              // 2M
  ushort* ktb  = yb   + (size_t)2 * MEG;              // 2M  [B*NH][64][T]
  ushort* k2tb = ktb  + (size_t)2 * MEG;              // 2M
  ushort* g1b  = k2tb + (size_t)2 * MEG;              // 128K: [32][64][64] bf16
  ushort* g2b  = g1b  + (size_t)(MEG / 8);            // 128K
  float*  csb  = (float*)(g2b + (size_t)(MEG / 8));   // [2][32][64] fp32
  ushort* wob  = wcat + (size_t)5 * MEG;

  // 1. cast everything to bf16
  cast_all<<<2048, 256, 0, stream>>>(x, Wq, Wk, Wv, Wq2, Wk2, Wo, xb, wcat);

  // 2. fused projections (+ transposed K, K2 for gram), BM=64/BK=64, 1280 blocks
  gemm_proj<<<1280, 256, 0, stream>>>(
      xb, wcat, qb, kb, q2b, k2b, vtb, ktb, k2tb);

  // 3. Gram matrices + colsums
  gram<<<64, 256, 0, stream>>>(ktb, k2tb, g1b, g2b, csb);

  // 4. fused attention (1024 blocks, 3/CU, balanced sweeps, setprio)
  attn_fused<<<1024, 256, 0, stream>>>(qb, kb, q2b, k2b, vtb, yb,
                                       g1b, g2b, csb, mixture, qsc);

  // 5. output projection (fp32 out), 512 blocks
  gemm_out<<<512, 256, 0, stream>>>(yb, wob, out);
}

// Round 13
// 105.489 us; speedup vs baseline: 1.0944x; 1.0391x over previous
//
#include <hip/hip_runtime.h>
#include <hip/hip_bf16.h>
#include <stdint.h>

#define TS 1024   // T
#define CS 1024   // C
#define NH 16
#define DHEAD 64
#define NBATCH 2
#define EPSV 1e-5f
#define MEG 1048576

typedef __bf16 bf16x8 __attribute__((ext_vector_type(8)));
typedef float  f32x4  __attribute__((ext_vector_type(4)));

#define MFMA(a, b, c) __builtin_amdgcn_mfma_f32_16x16x32_bf16((a), (b), (c), 0, 0, 0)

__device__ __forceinline__ float bf2f(ushort u){
  union { uint32_t i; float f; } v; v.i = ((uint32_t)u) << 16; return v.f;
}
__device__ __forceinline__ ushort f2bf(float f){
  union { float f; uint32_t i; } v; v.f = f;
  uint32_t r = v.i + 0x7FFFu + ((v.i >> 16) & 1u);
  return (ushort)(r >> 16);
}

// async global->LDS, 16B per lane. LDS dest wave-uniform base + lane*16B (linear);
// global src per-lane (enables pre-swizzled-source LDS layouts).
__device__ __forceinline__ void gl_lds16(const ushort* g, ushort* l) {
  __builtin_amdgcn_global_load_lds(
      (const __attribute__((address_space(1))) void*)g,
      (__attribute__((address_space(3))) void*)l, 16, 0, 0);
}

// ---------------- fused cast fp32 -> bf16 of all 7 tensors ----------------
__global__ __launch_bounds__(256)
void cast_all(const float* __restrict__ x,
              const float* __restrict__ Wq, const float* __restrict__ Wk,
              const float* __restrict__ Wv, const float* __restrict__ Wq2,
              const float* __restrict__ Wk2, const float* __restrict__ Wo,
              ushort* __restrict__ xb, ushort* __restrict__ wcat)
{
  const int XC = 524288, TOT = 2097152;
  for (int idx = blockIdx.x * 256 + threadIdx.x; idx < TOT; idx += 524288) {
    const float* s; ushort* d; int c;
    if (idx < XC) { s = x; d = xb; c = idx; }
    else {
      int r = idx - XC; int w = r >> 18; c = r & 262143;
      switch (w) {
        case 0:  s = Wq;  d = wcat;           break;
        case 1:  s = Wk;  d = wcat + 1*MEG;   break;
        case 2:  s = Wv;  d = wcat + 4*MEG;   break;
        case 3:  s = Wq2; d = wcat + 2*MEG;   break;
        case 4:  s = Wk2; d = wcat + 3*MEG;   break;
        default: s = Wo;  d = wcat + 5*MEG;   break;
      }
    }
    float4 v = *(const float4*)(s + (size_t)c * 4);
    ushort4 o; o.x = f2bf(v.x); o.y = f2bf(v.y); o.z = f2bf(v.z); o.w = f2bf(v.w);
    *(ushort4*)(d + (size_t)c * 4) = o;
  }
}

#define BN 128

// ---------------- fused projection GEMM: [x]@[Wq;Wk;Wq2;Wk2;Wv]^T ----------------
// BM=64 x BN=128, BK=64, single-buffered (24KB LDS, high block-TLP hides the
// barrier drain; explicit dbuf at 64KB measured WORSE). 1D grid 1280, XCD-swizzled.
__global__ __launch_bounds__(256, 2)
void gemm_proj(const ushort* __restrict__ A, const ushort* __restrict__ Bt,
               ushort* __restrict__ qb, ushort* __restrict__ kb,
               ushort* __restrict__ q2b, ushort* __restrict__ k2b,
               ushort* __restrict__ vtb,
               ushort* __restrict__ ktb, ushort* __restrict__ k2tb)
{
  __shared__ ushort a_s[64 * 64];    // [64 rows][64 cols] swz g^=row&7 (8KB)
  __shared__ ushort b_s[128 * 64];   // 16KB

  const int bid = blockIdx.x;
  const int s   = (bid & 7) * 160 + (bid >> 3);   // bijective, 1280%8==0
  const int n0  = (s >> 5) * BN;                  // x in [5c, 5c+5) per XCD c
  const int m0  = (s & 31) * 64;

  const int t  = threadIdx.x;
  const int w  = t >> 6, l = t & 63;
  const int wr = w >> 1, wc = w & 1;
  const int l15 = l & 15, l4 = l >> 4;
  const int r8 = l >> 3, g7 = l & 7;

  f32x4 acc[2][4] = {};

  for (int k0 = 0; k0 < CS; k0 += 64) {
    #pragma unroll
    for (int i = 0; i < 2; ++i) {
      int issue = w * 2 + i;              // 0..7
      int row   = issue * 8 + r8;         // 0..63
      int gs    = g7 ^ (row & 7);
      gl_lds16(&A[(size_t)(m0 + row) * CS + k0 + gs * 8], &a_s[issue * 512]);
    }
    #pragma unroll
    for (int i = 0; i < 4; ++i) {
      int issue = w * 4 + i;              // 0..15
      int row   = issue * 8 + r8;         // 0..127
      int gs    = g7 ^ (row & 7);
      gl_lds16(&Bt[(size_t)(n0 + row) * CS + k0 + gs * 8], &b_s[issue * 512]);
    }
    __syncthreads();

    #pragma unroll
    for (int ks = 0; ks < 2; ++ks) {
      bf16x8 af[2], bfr[4];
      #pragma unroll
      for (int mi = 0; mi < 2; ++mi) {
        int row = wr * 32 + mi * 16 + l15;
        int gl  = (ks * 4 + l4) ^ (row & 7);
        af[mi] = *(const bf16x8*)&a_s[row * 64 + gl * 8];
      }
      #pragma unroll
      for (int ni = 0; ni < 4; ++ni) {
        int row = wc * 64 + ni * 16 + l15;
        int gl  = (ks * 4 + l4) ^ (row & 7);
        bfr[ni] = *(const bf16x8*)&b_s[row * 64 + gl * 8];
      }
      #pragma unroll
      for (int mi = 0; mi < 2; ++mi)
        #pragma unroll
        for (int ni = 0; ni < 4; ++ni)
          acc[mi][ni] = MFMA(af[mi], bfr[ni], acc[mi][ni]);
    }

    __syncthreads();
  }

  #pragma unroll
  for (int mi = 0; mi < 2; ++mi) {
    #pragma unroll
    for (int ni = 0; ni < 4; ++ni) {
      int col  = n0 + wc * 64 + ni * 16 + l15;
      int row0 = m0 + wr * 32 + mi * 16 + l4 * 4;
      int seg  = col >> 10, cc = col & (CS - 1);
      if (seg < 4) {
        ushort* dst = (seg == 0) ? qb : (seg == 1) ? kb : (seg == 2) ? q2b : k2b;
        float sc = (seg & 1) ? 1.f : 0.125f;   // fold 1/sqrt(Dh) into q, q2
        #pragma unroll
        for (int e = 0; e < 4; ++e)
          dst[(size_t)(row0 + e) * CS + cc] = f2bf(acc[mi][ni][e] * sc);
        if (seg == 1 || seg == 3) {
          int bb = row0 >> 10, tt = row0 & (TS - 1);
          int hh = cc >> 6, dd = cc & (DHEAD - 1);
          ushort* td = (seg == 1) ? ktb : k2tb;
          ushort4 o;
          o.x = f2bf(acc[mi][ni][0]); o.y = f2bf(acc[mi][ni][1]);
          o.z = f2bf(acc[mi][ni][2]); o.w = f2bf(acc[mi][ni][3]);
          *(ushort4*)&td[(((size_t)(bb * NH + hh) * DHEAD + dd) * TS) + tt] = o;
        }
      } else {
        int bb = row0 >> 10, tt = row0 & (TS - 1);
        int hh = cc >> 6, dd = cc & (DHEAD - 1);
        ushort4 o;
        o.x = f2bf(acc[mi][ni][0]); o.y = f2bf(acc[mi][ni][1]);
        o.z = f2bf(acc[mi][ni][2]); o.w = f2bf(acc[mi][ni][3]);
        *(ushort4*)&vtb[(((size_t)(bb * NH + hh) * DHEAD + dd) * TS) + tt] = o;
      }
    }
  }
}

// ---------------- out-projection GEMM: out = y @ Wo^T (fp32 out) --------------
// v4: BM=64 x BN=64, BK=64 (16 iters, half the barrier drains of BK=32),
// granule-XOR swizzled LDS ([64][64] row-major would be 16-way bank conflict).
// Grid 512 (2 blocks/CU), 1D XCD-swizzled.
__global__ __launch_bounds__(256, 2)
void gemm_out(const ushort* __restrict__ A, const ushort* __restrict__ Bt,
              float* __restrict__ C)
{
  __shared__ ushort a_s[64 * 64];   // 8KB, swz g^=row&7
  __shared__ ushort b_s[64 * 64];   // 8KB

  const int bid = blockIdx.x;
  const int s   = (bid & 7) * 64 + (bid >> 3);    // bijective, 512%8==0
  const int n0  = (s >> 5) * 64;
  const int m0  = (s & 31) * 64;

  const int t  = threadIdx.x;
  const int w  = t >> 6, l = t & 63;
  const int wr = w >> 1, wc = w & 1;
  const int l15 = l & 15, l4 = l >> 4;
  const int r8 = l >> 3, g7 = l & 7;

  f32x4 acc[2][2] = {};

  for (int k0 = 0; k0 < CS; k0 += 64) {
    #pragma unroll
    for (int i = 0; i < 2; ++i) {
      int issue = w * 2 + i;              // 0..7
      int row   = issue * 8 + r8;         // 0..63
      int gs    = g7 ^ (row & 7);
      gl_lds16(&A [(size_t)(m0 + row) * CS + k0 + gs * 8], &a_s[issue * 512]);
      gl_lds16(&Bt[(size_t)(n0 + row) * CS + k0 + gs * 8], &b_s[issue * 512]);
    }
    __syncthreads();

    #pragma unroll
    for (int ks = 0; ks < 2; ++ks) {
      bf16x8 af[2], bfr[2];
      #pragma unroll
      for (int mi = 0; mi < 2; ++mi) {
        int row = wr * 32 + mi * 16 + l15;
        int gl  = (ks * 4 + l4) ^ (row & 7);
        af[mi] = *(const bf16x8*)&a_s[row * 64 + gl * 8];
      }
      #pragma unroll
      for (int ni = 0; ni < 2; ++ni) {
        int row = wc * 32 + ni * 16 + l15;
        int gl  = (ks * 4 + l4) ^ (row & 7);
        bfr[ni] = *(const bf16x8*)&b_s[row * 64 + gl * 8];
      }
      #pragma unroll
      for (int mi = 0; mi < 2; ++mi)
        #pragma unroll
        for (int ni = 0; ni < 2; ++ni)
          acc[mi][ni] = MFMA(af[mi], bfr[ni], acc[mi][ni]);
    }

    __syncthreads();
  }

  #pragma unroll
  for (int mi = 0; mi < 2; ++mi)
    #pragma unroll
    for (int ni = 0; ni < 2; ++ni)
      #pragma unroll
      for (int e = 0; e < 4; ++e)
        C[(size_t)(m0 + wr * 32 + mi * 16 + l4 * 4 + e) * CS +
          n0 + wc * 32 + ni * 16 + l15] = acc[mi][ni][e];
}

// ---------------- Gram kernel: G = K^T K (64x64, bf16 out) + colsum(K) ----------
__global__ __launch_bounds__(256, 2)
void gram(const ushort* __restrict__ ktb, const ushort* __restrict__ k2tb,
          ushort* __restrict__ g1b, ushort* __restrict__ g2b,
          float* __restrict__ csb)
{
  __shared__ ushort t_s[64 * 128];   // [64 d][128 t], granule-swizzled g ^= d&15

  const int mat = blockIdx.x & 1, z = blockIdx.x >> 1;
  const ushort* S = (mat ? k2tb : ktb) + (size_t)z * DHEAD * TS;

  const int t = threadIdx.x, w = t >> 6, l = t & 63;
  const int l15 = l & 15, l4 = l >> 4;

  f32x4 acc[4] = {};
  float csacc = 0.f;

  for (int tt = 0; tt < 8; ++tt) {
    const int t0 = tt * 128;
    __syncthreads();
    #pragma unroll
    for (int i = 0; i < 4; ++i) {
      int issue = w * 4 + i;
      int row = issue * 4 + l4;
      int gs  = l15 ^ (row & 15);
      gl_lds16(&S[(size_t)row * TS + t0 + gs * 8], &t_s[issue * 512]);
    }
    __syncthreads();

    {
      int r = w * 16 + l15;
      #pragma unroll
      for (int j = 0; j < 4; ++j) {
        int gg = ((l4 * 4 + j) ^ (r & 15)) * 8;
        uint4 vv = *(const uint4*)&t_s[r * 128 + gg];
        const ushort* pu = (const ushort*)&vv;
        #pragma unroll
        for (int e2 = 0; e2 < 8; ++e2) csacc += bf2f(pu[e2]);
      }
    }

    #pragma unroll
    for (int ks = 0; ks < 4; ++ks) {
      int ar = w * 16 + l15;
      bf16x8 af = *(const bf16x8*)&t_s[ar * 128 + ((ks * 4 + l4) ^ (ar & 15)) * 8];
      #pragma unroll
      for (int ni = 0; ni < 4; ++ni) {
        int br = ni * 16 + l15;
        bf16x8 bf_ = *(const bf16x8*)&t_s[br * 128 + ((ks * 4 + l4) ^ (br & 15)) * 8];
        acc[ni] = MFMA(af, bf_, acc[ni]);
      }
    }
  }

  csacc += __shfl_xor(csacc, 16);
  csacc += __shfl_xor(csacc, 32);
  if (l4 == 0)
    csb[(mat * 32 + z) * 64 + w * 16 + l15] = csacc;

  ushort* G = (mat ? g2b : g1b) + (size_t)z * 4096;
  #pragma unroll
  for (int ni = 0; ni < 4; ++ni)
    #pragma unroll
    for (int e = 0; e < 4; ++e)
      G[(w * 16 + l4 * 4 + e) * 64 + ni * 16 + l15] = f2bf(acc[ni][e]);
}

// ---------------- fused attention v9: R10 structure + balanced sweeps ----------
// Block = one head z, one 32-row Q-tile (1024 blocks). Pair p = w>>1 handles kv
// cols [p*32,p*32+32) of the shared 64-kv tile; wr = w&1 is 16-row group.
// No-max softmax => pair contributions additive; Gram-trick stats.
// LDS 53KB -> 3 blocks/CU. Per iter: prefetch K/V(i+1) -> QK^T -> softmax ->
// PV -> ONE barrier. v9: balanced sweeps only (per-CU totals ~35 iters for
// every qq); NO setprio (R12 showed it hurts here: 4 waves are barrier-locked
// each iter = m190's lockstep regime, not m191's phase-diverse one).
__global__ __launch_bounds__(256, 3)
void attn_fused(const ushort* __restrict__ qb, const ushort* __restrict__ kb,
                const ushort* __restrict__ q2b, const ushort* __restrict__ k2b,
                const ushort* __restrict__ vtb, ushort* __restrict__ yb,
                const ushort* __restrict__ g1b, const ushort* __restrict__ g2b,
                const float* __restrict__ csb,
                const float* __restrict__ mixture, const float* __restrict__ qsc)
{
  __shared__ ushort kbuf [2][4096];  // K tile [64 kv][64 d] swz g^=kv&7 (buf1: Q2 in prologue)
  __shared__ ushort k2buf[2][4096];  // K2 tile
  __shared__ ushort vbuf [2][4096];  // V tile [64 d][64 kv] swz g^=d&7
  __shared__ ushort p_s  [2 * 32 * 40]; // P per pair [32 r][40] pad (Q in prologue, first 4KB)

  const int idx  = blockIdx.x;
  const int pp   = idx >> 8;                     // 0..3 sweep
  const int base = idx & 255;
  const int xcd  = base & 7;
  const int mm   = base >> 3;                    // 0..31
  const int qq   = mm & 7;
  const int z    = (mm >> 3) * 8 + xcd;          // head id, affine to XCD
  // balanced sweeps: per-CU (fixed qq) totals ~35 iters for every qq
  const int q32  = (pp == 0) ? (31 - qq) : (pp == 1) ? qq
                 : (pp == 2) ? (23 - qq) : (8 + qq);
  const int b    = z >> 4, h = z & 15;
  const int m0   = q32 * 32;
  const int nkv  = (q32 >> 1) + 1;               // # 64-kv tiles needed (causal)

  const ushort* Q  = qb  + (size_t)b * TS * CS + h * DHEAD;
  const ushort* Q2 = q2b + (size_t)b * TS * CS + h * DHEAD;
  const ushort* K  = kb  + (size_t)b * TS * CS + h * DHEAD;
  const ushort* K2 = k2b + (size_t)b * TS * CS + h * DHEAD;
  const ushort* Vt = vtb + (size_t)z * DHEAD * TS;
  const ushort* G1 = g1b + (size_t)z * 4096;
  const ushort* G2 = g2b + (size_t)z * 4096;
  ushort* Y = yb + (size_t)b * TS * CS + h * DHEAD;

  const int t = threadIdx.x, w = t >> 6, l = t & 63;
  const int l15 = l & 15, l4 = l >> 4;
  const int r8 = l >> 3, g7 = l & 7;
  const int p  = w >> 1, wr = w & 1;
  const int qrow = wr * 16 + l15;                // local q-row 0..31

  const float L2E = 1.44269504f;
  const float gm = 1.f / (1.f + __expf(-mixture[0]));
  const float mq2 = gm * qsc[0] * L2E;
  const float om2 = (1.f - gm) * L2E;

  auto stage_k = [&](int ti, int bs) {
    const int t0 = ti * 64;
    #pragma unroll
    for (int i = 0; i < 2; ++i) {
      int issue = w * 2 + i;
      int row = issue * 8 + r8;                  // kv row 0..63
      int gs  = g7 ^ (row & 7);
      gl_lds16(&K [(size_t)(t0 + row) * CS + gs * 8], &kbuf [bs][issue * 512]);
      gl_lds16(&K2[(size_t)(t0 + row) * CS + gs * 8], &k2buf[bs][issue * 512]);
    }
  };
  auto stage_v = [&](int ti, int bs) {
    const int t0 = ti * 64;
    #pragma unroll
    for (int i = 0; i < 2; ++i) {
      int issue = w * 2 + i;
      int row = issue * 8 + r8;                  // d row 0..63
      int gs  = g7 ^ (row & 7);
      gl_lds16(&Vt[(size_t)row * TS + t0 + gs * 8], &vbuf[bs][issue * 512]);
    }
  };

  // ---- prologue: Q -> p_s (4KB), Q2 -> kbuf[1], K0/K2_0 -> buf0, V0 -> vbuf0 ----
  {
    int row = w * 8 + r8;                        // 0..31
    int gs  = g7 ^ (row & 7);
    gl_lds16(&Q [(size_t)(m0 + row) * CS + gs * 8], &p_s[w * 512]);
    gl_lds16(&Q2[(size_t)(m0 + row) * CS + gs * 8], &kbuf[1][w * 512]);
  }
  stage_k(0, 0);
  stage_v(0, 0);
  __syncthreads();

  // Q fragments (B-operand: 16 rows of this wave over l15, k-slice over l4)
  bf16x8 fq[2], fq2[2];
  #pragma unroll
  for (int ks = 0; ks < 2; ++ks) {
    int gg = ((ks * 4 + l4) ^ (qrow & 7)) * 8;
    fq [ks] = *(const bf16x8*)&p_s[qrow * 64 + gg];
    fq2[ks] = *(const bf16x8*)&kbuf[1][qrow * 64 + gg];
  }

  // U = G @ Q^T (G from global, row-major A-frags); lane: d = ni*16+l4*4+e, col=qrow
  f32x4 U1[4] = {}, U2[4] = {};
  #pragma unroll
  for (int ks = 0; ks < 2; ++ks)
    #pragma unroll
    for (int ni = 0; ni < 4; ++ni) {
      bf16x8 bg = *(const bf16x8*)&G1[(ni * 16 + l15) * 64 + ks * 32 + l4 * 8];
      U1[ni] = MFMA(bg, fq[ks], U1[ni]);
    }
  #pragma unroll
  for (int ks = 0; ks < 2; ++ks)
    #pragma unroll
    for (int ni = 0; ni < 4; ++ni) {
      bf16x8 bg = *(const bf16x8*)&G2[(ni * 16 + l15) * 64 + ks * 32 + l4 * 8];
      U2[ni] = MFMA(bg, fq2[ks], U2[ni]);
    }

  // per-lane stats: ssq = sum_d U[d]*q[d]; mudot = sum_d q[d]*cs[d]
  float ssq1 = 0.f, md1 = 0.f, ssq2 = 0.f, md2 = 0.f;
  #pragma unroll
  for (int ni = 0; ni < 4; ++ni) {
    int gsq = (ni * 2 + (l4 >> 1)) ^ (qrow & 7);
    int off = qrow * 64 + gsq * 8 + (l4 & 1) * 4;
    ushort qa[4], qb2[4];
    *(uint2*)qa  = *(const uint2*)&p_s[off];
    *(uint2*)qb2 = *(const uint2*)&kbuf[1][off];
    float c1[4], c2[4];
    *(float4*)c1 = *(const float4*)&csb[z * 64 + ni * 16 + l4 * 4];
    *(float4*)c2 = *(const float4*)&csb[2048 + z * 64 + ni * 16 + l4 * 4];
    #pragma unroll
    for (int e = 0; e < 4; ++e) {
      float qv1 = bf2f(qa[e]), qv2 = bf2f(qb2[e]);
      ssq1 = fmaf(U1[ni][e], qv1, ssq1); md1 = fmaf(qv1, c1[e], md1);
      ssq2 = fmaf(U2[ni][e], qv2, ssq2); md2 = fmaf(qv2, c2[e], md2);
    }
  }
  ssq1 += __shfl_xor(ssq1, 16); md1 += __shfl_xor(md1, 16);
  ssq2 += __shfl_xor(ssq2, 16); md2 += __shfl_xor(md2, 16);
  ssq1 += __shfl_xor(ssq1, 32); md1 += __shfl_xor(md1, 32);
  ssq2 += __shfl_xor(ssq2, 32); md2 += __shfl_xor(md2, 32);

  const float mu1 = md1 * (1.f / TS), mu2 = md2 * (1.f / TS);
  const float va1 = (ssq1 - (float)TS * mu1 * mu1) * (1.f / (TS - 1));
  const float va2 = (ssq2 - (float)TS * mu2 * mu2) * (1.f / (TS - 1));
  const float iv1 = 1.f / (sqrtf(fmaxf(va1, 0.f)) + EPSV);
  const float iv2 = 1.f / (sqrtf(fmaxf(va2, 0.f)) + EPSV);
  __syncthreads();                   // release p_s (Q) + kbuf[1] (Q2)

  // ---- kv loop: prefetch K/V(i+1) -> QK^T -> softmax -> PV -> ONE barrier ----
  float lrow = 0.f;
  f32x4 accO[4] = {};                // lane: row = wr*16 + l4*4+e, d = ni*16+l15

  for (int i = 0; i < nkv; ++i) {
    const int t0  = i * 64;
    const int cur = i & 1;
    if (i + 1 < nkv) { stage_k(i + 1, cur ^ 1); stage_v(i + 1, cur ^ 1); }

    const ushort* ks_ = kbuf [cur];
    const ushort* k2s_= k2buf[cur];

    // QK^T swapped: A = K rows (pair half), B = Q rows; kv = p*32+ni*16+l4*4+e
    f32x4 a1[2] = {}, a2[2] = {};
    #pragma unroll
    for (int ks = 0; ks < 2; ++ks) {
      bf16x8 bk[2], bk2[2];
      #pragma unroll
      for (int ni = 0; ni < 2; ++ni) {
        int j  = p * 32 + ni * 16 + l15;
        int gg = ((ks * 4 + l4) ^ (j & 7)) * 8;
        bk [ni] = *(const bf16x8*)&ks_ [j * 64 + gg];
        bk2[ni] = *(const bf16x8*)&k2s_[j * 64 + gg];
      }
      #pragma unroll
      for (int ni = 0; ni < 2; ++ni) {
        a1[ni] = MFMA(bk [ni], fq [ks], a1[ni]);
        a2[ni] = MFMA(bk2[ni], fq2[ks], a2[ni]);
      }
    }

    // normalize + gate + causal mask + exp2; pack & store P (pair-local rows)
    const int grow = m0 + qrow;
    #pragma unroll
    for (int ni = 0; ni < 2; ++ni) {
      float pe[4];
      #pragma unroll
      for (int e = 0; e < 4; ++e) {
        float n1 = (a1[ni][e] - mu1) * iv1;
        float n2 = (a2[ni][e] - mu2) * iv2;
        float sc = n1 * fmaf(mq2, n2, om2);
        float pv = exp2f(sc);
        int gcol = t0 + p * 32 + ni * 16 + l4 * 4 + e;
        pv = (gcol <= grow) ? pv : 0.f;
        lrow += pv;
        pe[e] = pv;
      }
      uint32_t pk01, pk23;
      asm("v_cvt_pk_bf16_f32 %0, %1, %2" : "=v"(pk01) : "v"(pe[0]), "v"(pe[1]));
      asm("v_cvt_pk_bf16_f32 %0, %1, %2" : "=v"(pk23) : "v"(pe[2]), "v"(pe[3]));
      uint2 pk; pk.x = pk01; pk.y = pk23;
      *(uint2*)&p_s[p * 1280 + qrow * 40 + ni * 16 + l4 * 4] = pk;
    }

    // PV: A = P[own rows][pair kv-half], B = V[d][pair kv-half]; same-wave LDS dep
    {
      bf16x8 ap = *(const bf16x8*)&p_s[p * 1280 + qrow * 40 + l4 * 8];
      #pragma unroll
      for (int ni = 0; ni < 4; ++ni) {
        int d  = ni * 16 + l15;
        int gg = ((p * 4 + l4) ^ (d & 7)) * 8;
        bf16x8 bv = *(const bf16x8*)&vbuf[cur][d * 64 + gg];
        accO[ni] = MFMA(ap, bv, accO[ni]);
      }
    }

    __syncthreads();   // drains prefetches + releases cur buffers
  }

  // ---- epilogue: combine wave pairs (additive, no-max), normalize, write ----
  lrow += __shfl_xor(lrow, 16);
  lrow += __shfl_xor(lrow, 32);      // row-sum of this pair's kv half

  float* fb = (float*)kbuf;          // [32][64] f32 partial O (8KB of 16KB)
  float* fl = (float*)k2buf;         // [32] f32 partial lrow
  if (p == 1) {
    #pragma unroll
    for (int ni = 0; ni < 4; ++ni)
      #pragma unroll
      for (int e = 0; e < 4; ++e)
        fb[(wr * 16 + l4 * 4 + e) * 64 + ni * 16 + l15] = accO[ni][e];
    if (l4 == 0) fl[qrow] = lrow;
  }
  __syncthreads();
  if (p == 0) {
    float lt = lrow + fl[qrow];      // total row denom (lane l15-indexed)
    float il[4];
    #pragma unroll
    for (int e = 0; e < 4; ++e)
      il[e] = 1.f / __shfl(lt, l4 * 4 + e);
    #pragma unroll
    for (int ni = 0; ni < 4; ++ni)
      #pragma unroll
      for (int e = 0; e < 4; ++e) {
        float o = accO[ni][e] + fb[(wr * 16 + l4 * 4 + e) * 64 + ni * 16 + l15];
        Y[(size_t)(m0 + wr * 16 + l4 * 4 + e) * CS + ni * 16 + l15] = f2bf(o * il[e]);
      }
  }
}

// ---------------- launcher ----------------
extern "C" void kernel_launch(void* const* d_in, const int* in_sizes, int n_in,
                              void* d_out, int out_size, void* d_ws, size_t ws_size,
                              hipStream_t stream) {
  const float* x    = (const float*)d_in[0];
  const float* Wq   = (const float*)d_in[1];
  const float* Wk   = (const float*)d_in[2];
  const float* Wv   = (const float*)d_in[3];
  const float* Wq2  = (const float*)d_in[4];
  const float* Wk2  = (const float*)d_in[5];
  const float* Wo   = (const float*)d_in[6];
  const float* mixture = (const float*)d_in[7];
  const float* qsc  = (const float*)d_in[8];
  float* out = (float*)d_out;

  ushort* ws = (ushort*)d_ws;
  ushort* xb   = ws;                                  // 2M
  ushort* wcat = xb   + (size_t)2 * MEG;              // 6M: wq,wk,wq2,wk2,wv,wo
  ushort* qb   = wcat + (size_t)6 * MEG;              // 2M (pre-scaled by 1/8)
  ushort* q2b  = qb   + (size_t)2 * MEG;              // 2M (pre-scaled by 1/8)
  ushort* kb   = q2b  + (size_t)2 * MEG;              // 2M
  ushort* k2b  = kb   + (size_t)2 * MEG;              // 2M
  ushort* vtb  = k2b  + (size_t)2 * MEG;              // 2M  [B*NH][64][T]
  ushort* yb   = vtb  + (size_t)2 * MEG;              // 2M
  ushort* ktb  = yb   + (size_t)2 * MEG;              // 2M  [B*NH][64][T]
  ushort* k2tb = ktb  + (size_t)2 * MEG;              // 2M
  ushort* g1b  = k2tb + (size_t)2 * MEG;              // 128K: [32][64][64] bf16
  ushort* g2b  = g1b  + (size_t)(MEG / 8);            // 128K
  float*  csb  = (float*)(g2b + (size_t)(MEG / 8));   // [2][32][64] fp32
  ushort* wob  = wcat + (size_t)5 * MEG;

  // 1. cast everything to bf16
  cast_all<<<2048, 256, 0, stream>>>(x, Wq, Wk, Wv, Wq2, Wk2, Wo, xb, wcat);

  // 2. fused projections (+ transposed K, K2 for gram), BM=64/BK=64, 1280 blocks
  gemm_proj<<<1280, 256, 0, stream>>>(
      xb, wcat, qb, kb, q2b, k2b, vtb, ktb, k2tb);

  // 3. Gram matrices + colsums
  gram<<<64, 256, 0, stream>>>(ktb, k2tb, g1b, g2b, csb);

  // 4. fused attention (1024 blocks, 3/CU, balanced sweeps, no setprio)
  attn_fused<<<1024, 256, 0, stream>>>(qb, kb, q2b, k2b, vtb, yb,
                                       g1b, g2b, csb, mixture, qsc);

  // 5. output projection (fp32 out), 512 blocks, BK=64
  gemm_out<<<512, 256, 0, stream>>>(yb, wob, out);
}

// Round 14
// 104.812 us; speedup vs baseline: 1.1015x; 1.0065x over previous
//
#include <hip/hip_runtime.h>
#include <hip/hip_bf16.h>
#include <stdint.h>

#define TS 1024   // T
#define CS 1024   // C
#define NH 16
#define DHEAD 64
#define NBATCH 2
#define EPSV 1e-5f
#define MEG 1048576

typedef __bf16 bf16x8 __attribute__((ext_vector_type(8)));
typedef float  f32x4  __attribute__((ext_vector_type(4)));

#define MFMA(a, b, c) __builtin_amdgcn_mfma_f32_16x16x32_bf16((a), (b), (c), 0, 0, 0)

__device__ __forceinline__ float bf2f(ushort u){
  union { uint32_t i; float f; } v; v.i = ((uint32_t)u) << 16; return v.f;
}
__device__ __forceinline__ ushort f2bf(float f){
  union { float f; uint32_t i; } v; v.f = f;
  uint32_t r = v.i + 0x7FFFu + ((v.i >> 16) & 1u);
  return (ushort)(r >> 16);
}

// async global->LDS, 16B per lane. LDS dest wave-uniform base + lane*16B (linear);
// global src per-lane (enables pre-swizzled-source LDS layouts).
__device__ __forceinline__ void gl_lds16(const ushort* g, ushort* l) {
  __builtin_amdgcn_global_load_lds(
      (const __attribute__((address_space(1))) void*)g,
      (__attribute__((address_space(3))) void*)l, 16, 0, 0);
}

// ---------------- fused cast fp32 -> bf16 of all 7 tensors ----------------
__global__ __launch_bounds__(256)
void cast_all(const float* __restrict__ x,
              const float* __restrict__ Wq, const float* __restrict__ Wk,
              const float* __restrict__ Wv, const float* __restrict__ Wq2,
              const float* __restrict__ Wk2, const float* __restrict__ Wo,
              ushort* __restrict__ xb, ushort* __restrict__ wcat)
{
  const int XC = 524288, TOT = 2097152;
  for (int idx = blockIdx.x * 256 + threadIdx.x; idx < TOT; idx += 524288) {
    const float* s; ushort* d; int c;
    if (idx < XC) { s = x; d = xb; c = idx; }
    else {
      int r = idx - XC; int w = r >> 18; c = r & 262143;
      switch (w) {
        case 0:  s = Wq;  d = wcat;           break;
        case 1:  s = Wk;  d = wcat + 1*MEG;   break;
        case 2:  s = Wv;  d = wcat + 4*MEG;   break;
        case 3:  s = Wq2; d = wcat + 2*MEG;   break;
        case 4:  s = Wk2; d = wcat + 3*MEG;   break;
        default: s = Wo;  d = wcat + 5*MEG;   break;
      }
    }
    float4 v = *(const float4*)(s + (size_t)c * 4);
    ushort4 o; o.x = f2bf(v.x); o.y = f2bf(v.y); o.z = f2bf(v.z); o.w = f2bf(v.w);
    *(ushort4*)(d + (size_t)c * 4) = o;
  }
}

#define BN 128

// ---------------- fused projection GEMM: [x]@[Wq;Wk;Wq2;Wk2;Wv]^T ----------------
// BM=64 x BN=128, BK=64, single-buffered (24KB LDS, high block-TLP hides the
// barrier drain; explicit dbuf at 64KB measured WORSE). 1D grid 1280, XCD-swizzled.
__global__ __launch_bounds__(256, 2)
void gemm_proj(const ushort* __restrict__ A, const ushort* __restrict__ Bt,
               ushort* __restrict__ qb, ushort* __restrict__ kb,
               ushort* __restrict__ q2b, ushort* __restrict__ k2b,
               ushort* __restrict__ vtb,
               ushort* __restrict__ ktb, ushort* __restrict__ k2tb)
{
  __shared__ ushort a_s[64 * 64];    // [64 rows][64 cols] swz g^=row&7 (8KB)
  __shared__ ushort b_s[128 * 64];   // 16KB

  const int bid = blockIdx.x;
  const int s   = (bid & 7) * 160 + (bid >> 3);   // bijective, 1280%8==0
  const int n0  = (s >> 5) * BN;                  // x in [5c, 5c+5) per XCD c
  const int m0  = (s & 31) * 64;

  const int t  = threadIdx.x;
  const int w  = t >> 6, l = t & 63;
  const int wr = w >> 1, wc = w & 1;
  const int l15 = l & 15, l4 = l >> 4;
  const int r8 = l >> 3, g7 = l & 7;

  f32x4 acc[2][4] = {};

  for (int k0 = 0; k0 < CS; k0 += 64) {
    #pragma unroll
    for (int i = 0; i < 2; ++i) {
      int issue = w * 2 + i;              // 0..7
      int row   = issue * 8 + r8;         // 0..63
      int gs    = g7 ^ (row & 7);
      gl_lds16(&A[(size_t)(m0 + row) * CS + k0 + gs * 8], &a_s[issue * 512]);
    }
    #pragma unroll
    for (int i = 0; i < 4; ++i) {
      int issue = w * 4 + i;              // 0..15
      int row   = issue * 8 + r8;         // 0..127
      int gs    = g7 ^ (row & 7);
      gl_lds16(&Bt[(size_t)(n0 + row) * CS + k0 + gs * 8], &b_s[issue * 512]);
    }
    __syncthreads();

    #pragma unroll
    for (int ks = 0; ks < 2; ++ks) {
      bf16x8 af[2], bfr[4];
      #pragma unroll
      for (int mi = 0; mi < 2; ++mi) {
        int row = wr * 32 + mi * 16 + l15;
        int gl  = (ks * 4 + l4) ^ (row & 7);
        af[mi] = *(const bf16x8*)&a_s[row * 64 + gl * 8];
      }
      #pragma unroll
      for (int ni = 0; ni < 4; ++ni) {
        int row = wc * 64 + ni * 16 + l15;
        int gl  = (ks * 4 + l4) ^ (row & 7);
        bfr[ni] = *(const bf16x8*)&b_s[row * 64 + gl * 8];
      }
      #pragma unroll
      for (int mi = 0; mi < 2; ++mi)
        #pragma unroll
        for (int ni = 0; ni < 4; ++ni)
          acc[mi][ni] = MFMA(af[mi], bfr[ni], acc[mi][ni]);
    }

    __syncthreads();
  }

  #pragma unroll
  for (int mi = 0; mi < 2; ++mi) {
    #pragma unroll
    for (int ni = 0; ni < 4; ++ni) {
      int col  = n0 + wc * 64 + ni * 16 + l15;
      int row0 = m0 + wr * 32 + mi * 16 + l4 * 4;
      int seg  = col >> 10, cc = col & (CS - 1);
      if (seg < 4) {
        ushort* dst = (seg == 0) ? qb : (seg == 1) ? kb : (seg == 2) ? q2b : k2b;
        float sc = (seg & 1) ? 1.f : 0.125f;   // fold 1/sqrt(Dh) into q, q2
        #pragma unroll
        for (int e = 0; e < 4; ++e)
          dst[(size_t)(row0 + e) * CS + cc] = f2bf(acc[mi][ni][e] * sc);
        if (seg == 1 || seg == 3) {
          int bb = row0 >> 10, tt = row0 & (TS - 1);
          int hh = cc >> 6, dd = cc & (DHEAD - 1);
          ushort* td = (seg == 1) ? ktb : k2tb;
          ushort4 o;
          o.x = f2bf(acc[mi][ni][0]); o.y = f2bf(acc[mi][ni][1]);
          o.z = f2bf(acc[mi][ni][2]); o.w = f2bf(acc[mi][ni][3]);
          *(ushort4*)&td[(((size_t)(bb * NH + hh) * DHEAD + dd) * TS) + tt] = o;
        }
      } else {
        int bb = row0 >> 10, tt = row0 & (TS - 1);
        int hh = cc >> 6, dd = cc & (DHEAD - 1);
        ushort4 o;
        o.x = f2bf(acc[mi][ni][0]); o.y = f2bf(acc[mi][ni][1]);
        o.z = f2bf(acc[mi][ni][2]); o.w = f2bf(acc[mi][ni][3]);
        *(ushort4*)&vtb[(((size_t)(bb * NH + hh) * DHEAD + dd) * TS) + tt] = o;
      }
    }
  }
}

// ---------------- out-projection GEMM: out = y @ Wo^T (fp32 out) --------------
// BM=64 x BN=64, BK=64, granule-XOR swizzled LDS. Grid 512, 1D XCD-swizzled.
__global__ __launch_bounds__(256, 2)
void gemm_out(const ushort* __restrict__ A, const ushort* __restrict__ Bt,
              float* __restrict__ C)
{
  __shared__ ushort a_s[64 * 64];   // 8KB, swz g^=row&7
  __shared__ ushort b_s[64 * 64];   // 8KB

  const int bid = blockIdx.x;
  const int s   = (bid & 7) * 64 + (bid >> 3);    // bijective, 512%8==0
  const int n0  = (s >> 5) * 64;
  const int m0  = (s & 31) * 64;

  const int t  = threadIdx.x;
  const int w  = t >> 6, l = t & 63;
  const int wr = w >> 1, wc = w & 1;
  const int l15 = l & 15, l4 = l >> 4;
  const int r8 = l >> 3, g7 = l & 7;

  f32x4 acc[2][2] = {};

  for (int k0 = 0; k0 < CS; k0 += 64) {
    #pragma unroll
    for (int i = 0; i < 2; ++i) {
      int issue = w * 2 + i;              // 0..7
      int row   = issue * 8 + r8;         // 0..63
      int gs    = g7 ^ (row & 7);
      gl_lds16(&A [(size_t)(m0 + row) * CS + k0 + gs * 8], &a_s[issue * 512]);
      gl_lds16(&Bt[(size_t)(n0 + row) * CS + k0 + gs * 8], &b_s[issue * 512]);
    }
    __syncthreads();

    #pragma unroll
    for (int ks = 0; ks < 2; ++ks) {
      bf16x8 af[2], bfr[2];
      #pragma unroll
      for (int mi = 0; mi < 2; ++mi) {
        int row = wr * 32 + mi * 16 + l15;
        int gl  = (ks * 4 + l4) ^ (row & 7);
        af[mi] = *(const bf16x8*)&a_s[row * 64 + gl * 8];
      }
      #pragma unroll
      for (int ni = 0; ni < 2; ++ni) {
        int row = wc * 32 + ni * 16 + l15;
        int gl  = (ks * 4 + l4) ^ (row & 7);
        bfr[ni] = *(const bf16x8*)&b_s[row * 64 + gl * 8];
      }
      #pragma unroll
      for (int mi = 0; mi < 2; ++mi)
        #pragma unroll
        for (int ni = 0; ni < 2; ++ni)
          acc[mi][ni] = MFMA(af[mi], bfr[ni], acc[mi][ni]);
    }

    __syncthreads();
  }

  #pragma unroll
  for (int mi = 0; mi < 2; ++mi)
    #pragma unroll
    for (int ni = 0; ni < 2; ++ni)
      #pragma unroll
      for (int e = 0; e < 4; ++e)
        C[(size_t)(m0 + wr * 32 + mi * 16 + l4 * 4 + e) * CS +
          n0 + wc * 32 + ni * 16 + l15] = acc[mi][ni][e];
}

// ---------------- Gram kernel: G = K^T K (64x64, bf16 out) + colsum(K) ----------
__global__ __launch_bounds__(256, 2)
void gram(const ushort* __restrict__ ktb, const ushort* __restrict__ k2tb,
          ushort* __restrict__ g1b, ushort* __restrict__ g2b,
          float* __restrict__ csb)
{
  __shared__ ushort t_s[64 * 128];   // [64 d][128 t], granule-swizzled g ^= d&15

  const int mat = blockIdx.x & 1, z = blockIdx.x >> 1;
  const ushort* S = (mat ? k2tb : ktb) + (size_t)z * DHEAD * TS;

  const int t = threadIdx.x, w = t >> 6, l = t & 63;
  const int l15 = l & 15, l4 = l >> 4;

  f32x4 acc[4] = {};
  float csacc = 0.f;

  for (int tt = 0; tt < 8; ++tt) {
    const int t0 = tt * 128;
    __syncthreads();
    #pragma unroll
    for (int i = 0; i < 4; ++i) {
      int issue = w * 4 + i;
      int row = issue * 4 + l4;
      int gs  = l15 ^ (row & 15);
      gl_lds16(&S[(size_t)row * TS + t0 + gs * 8], &t_s[issue * 512]);
    }
    __syncthreads();

    {
      int r = w * 16 + l15;
      #pragma unroll
      for (int j = 0; j < 4; ++j) {
        int gg = ((l4 * 4 + j) ^ (r & 15)) * 8;
        uint4 vv = *(const uint4*)&t_s[r * 128 + gg];
        const ushort* pu = (const ushort*)&vv;
        #pragma unroll
        for (int e2 = 0; e2 < 8; ++e2) csacc += bf2f(pu[e2]);
      }
    }

    #pragma unroll
    for (int ks = 0; ks < 4; ++ks) {
      int ar = w * 16 + l15;
      bf16x8 af = *(const bf16x8*)&t_s[ar * 128 + ((ks * 4 + l4) ^ (ar & 15)) * 8];
      #pragma unroll
      for (int ni = 0; ni < 4; ++ni) {
        int br = ni * 16 + l15;
        bf16x8 bf_ = *(const bf16x8*)&t_s[br * 128 + ((ks * 4 + l4) ^ (br & 15)) * 8];
        acc[ni] = MFMA(af, bf_, acc[ni]);
      }
    }
  }

  csacc += __shfl_xor(csacc, 16);
  csacc += __shfl_xor(csacc, 32);
  if (l4 == 0)
    csb[(mat * 32 + z) * 64 + w * 16 + l15] = csacc;

  ushort* G = (mat ? g2b : g1b) + (size_t)z * 4096;
  #pragma unroll
  for (int ni = 0; ni < 4; ++ni)
    #pragma unroll
    for (int e = 0; e < 4; ++e)
      G[(w * 16 + l4 * 4 + e) * 64 + ni * 16 + l15] = f2bf(acc[ni][e]);
}

// ---------------- fused attention v10: K2 in registers -> 37KB LDS -------------
// Block = one head z, one 32-row Q-tile (1024 blocks). Pair p = w>>1 handles kv
// cols [p*32,p*32+32); wr = w&1 is 16-row group. No-max softmax (additive pairs),
// Gram-trick stats. K2's MFMA A-frags are DIRECT per-lane global loads (L2-hot;
// LDS staging added nothing) -> LDS = K dbuf 16K + V dbuf 16K + P 5K = 37KB ->
// 4 blocks/CU if VGPR <= 128 (launch_bounds(256,3): allocator never forced to
// spill; occupancy branch visible in VGPR_Count). K2 regs double-buffered via
// wave-uniform parity branch (no runtime-indexed frag arrays). Next-tile K2
// loads drain for free at the existing barrier's vmcnt(0).
__global__ __launch_bounds__(256, 3)
void attn_fused(const ushort* __restrict__ qb, const ushort* __restrict__ kb,
                const ushort* __restrict__ q2b, const ushort* __restrict__ k2b,
                const ushort* __restrict__ vtb, ushort* __restrict__ yb,
                const ushort* __restrict__ g1b, const ushort* __restrict__ g2b,
                const float* __restrict__ csb,
                const float* __restrict__ mixture, const float* __restrict__ qsc)
{
  __shared__ ushort kbuf[2][4096];   // K tile [64 kv][64 d] swz g^=kv&7 (buf1: Q2 in prologue)
  __shared__ ushort vbuf[2][4096];   // V tile [64 d][64 kv] swz g^=d&7
  __shared__ ushort p_s [2 * 32 * 40]; // P per pair [32 r][40] pad (Q in prologue, first 4KB)

  const int idx  = blockIdx.x;
  const int pp   = idx >> 8;                     // 0..3 sweep
  const int base = idx & 255;
  const int xcd  = base & 7;
  const int mm   = base >> 3;                    // 0..31
  const int qq   = mm & 7;
  const int z    = (mm >> 3) * 8 + xcd;          // head id, affine to XCD
  // balanced sweeps: per-CU (fixed qq) totals ~35 iters for every qq
  const int q32  = (pp == 0) ? (31 - qq) : (pp == 1) ? qq
                 : (pp == 2) ? (23 - qq) : (8 + qq);
  const int b    = z >> 4, h = z & 15;
  const int m0   = q32 * 32;
  const int nkv  = (q32 >> 1) + 1;               // # 64-kv tiles needed (causal)

  const ushort* Q  = qb  + (size_t)b * TS * CS + h * DHEAD;
  const ushort* Q2 = q2b + (size_t)b * TS * CS + h * DHEAD;
  const ushort* K  = kb  + (size_t)b * TS * CS + h * DHEAD;
  const ushort* K2 = k2b + (size_t)b * TS * CS + h * DHEAD;
  const ushort* Vt = vtb + (size_t)z * DHEAD * TS;
  const ushort* G1 = g1b + (size_t)z * 4096;
  const ushort* G2 = g2b + (size_t)z * 4096;
  ushort* Y = yb + (size_t)b * TS * CS + h * DHEAD;

  const int t = threadIdx.x, w = t >> 6, l = t & 63;
  const int l15 = l & 15, l4 = l >> 4;
  const int r8 = l >> 3, g7 = l & 7;
  const int p  = w >> 1, wr = w & 1;
  const int qrow = wr * 16 + l15;                // local q-row 0..31

  const float L2E = 1.44269504f;
  const float gm = 1.f / (1.f + __expf(-mixture[0]));
  const float mq2 = gm * qsc[0] * L2E;
  const float om2 = (1.f - gm) * L2E;

  auto stage_k = [&](int ti, int bs) {
    const int t0 = ti * 64;
    #pragma unroll
    for (int i = 0; i < 2; ++i) {
      int issue = w * 2 + i;
      int row = issue * 8 + r8;                  // kv row 0..63
      int gs  = g7 ^ (row & 7);
      gl_lds16(&K[(size_t)(t0 + row) * CS + gs * 8], &kbuf[bs][issue * 512]);
    }
  };
  auto stage_v = [&](int ti, int bs) {
    const int t0 = ti * 64;
    #pragma unroll
    for (int i = 0; i < 2; ++i) {
      int issue = w * 2 + i;
      int row = issue * 8 + r8;                  // d row 0..63
      int gs  = g7 ^ (row & 7);
      gl_lds16(&Vt[(size_t)row * TS + t0 + gs * 8], &vbuf[bs][issue * 512]);
    }
  };

  // K2 A-frags (pair half): frag(ni,ks) = K2[t0 + p*32 + ni*16 + l15][ks*32 + l4*8 ..+8]
  bf16x8 k2A[2][2], k2B[2][2];
#define LOAD_K2(ti, dst)                                                        \
  {                                                                             \
    const int t0_ = (ti) * 64;                                                  \
    _Pragma("unroll")                                                           \
    for (int ni = 0; ni < 2; ++ni)                                              \
      _Pragma("unroll")                                                         \
      for (int ks = 0; ks < 2; ++ks)                                            \
        dst[ni][ks] = *(const bf16x8*)&K2[(size_t)(t0_ + p * 32 + ni * 16 + l15)\
                                          * CS + ks * 32 + l4 * 8];             \
  }

  // ---- prologue: Q -> p_s (4KB), Q2 -> kbuf[1], K0 -> kbuf0, V0 -> vbuf0,
  //      K2 tile0 -> k2A ----
  {
    int row = w * 8 + r8;                        // 0..31
    int gs  = g7 ^ (row & 7);
    gl_lds16(&Q [(size_t)(m0 + row) * CS + gs * 8], &p_s[w * 512]);
    gl_lds16(&Q2[(size_t)(m0 + row) * CS + gs * 8], &kbuf[1][w * 512]);
  }
  stage_k(0, 0);
  stage_v(0, 0);
  LOAD_K2(0, k2A);
  __syncthreads();

  // Q fragments (B-operand: 16 rows of this wave over l15, k-slice over l4)
  bf16x8 fq[2], fq2[2];
  #pragma unroll
  for (int ks = 0; ks < 2; ++ks) {
    int gg = ((ks * 4 + l4) ^ (qrow & 7)) * 8;
    fq [ks] = *(const bf16x8*)&p_s[qrow * 64 + gg];
    fq2[ks] = *(const bf16x8*)&kbuf[1][qrow * 64 + gg];
  }

  // U = G @ Q^T (G from global, row-major A-frags); lane: d = ni*16+l4*4+e, col=qrow
  f32x4 U1[4] = {}, U2[4] = {};
  #pragma unroll
  for (int ks = 0; ks < 2; ++ks)
    #pragma unroll
    for (int ni = 0; ni < 4; ++ni) {
      bf16x8 bg = *(const bf16x8*)&G1[(ni * 16 + l15) * 64 + ks * 32 + l4 * 8];
      U1[ni] = MFMA(bg, fq[ks], U1[ni]);
    }
  #pragma unroll
  for (int ks = 0; ks < 2; ++ks)
    #pragma unroll
    for (int ni = 0; ni < 4; ++ni) {
      bf16x8 bg = *(const bf16x8*)&G2[(ni * 16 + l15) * 64 + ks * 32 + l4 * 8];
      U2[ni] = MFMA(bg, fq2[ks], U2[ni]);
    }

  // per-lane stats: ssq = sum_d U[d]*q[d]; mudot = sum_d q[d]*cs[d]
  float ssq1 = 0.f, md1 = 0.f, ssq2 = 0.f, md2 = 0.f;
  #pragma unroll
  for (int ni = 0; ni < 4; ++ni) {
    int gsq = (ni * 2 + (l4 >> 1)) ^ (qrow & 7);
    int off = qrow * 64 + gsq * 8 + (l4 & 1) * 4;
    ushort qa[4], qb2[4];
    *(uint2*)qa  = *(const uint2*)&p_s[off];
    *(uint2*)qb2 = *(const uint2*)&kbuf[1][off];
    float c1[4], c2[4];
    *(float4*)c1 = *(const float4*)&csb[z * 64 + ni * 16 + l4 * 4];
    *(float4*)c2 = *(const float4*)&csb[2048 + z * 64 + ni * 16 + l4 * 4];
    #pragma unroll
    for (int e = 0; e < 4; ++e) {
      float qv1 = bf2f(qa[e]), qv2 = bf2f(qb2[e]);
      ssq1 = fmaf(U1[ni][e], qv1, ssq1); md1 = fmaf(qv1, c1[e], md1);
      ssq2 = fmaf(U2[ni][e], qv2, ssq2); md2 = fmaf(qv2, c2[e], md2);
    }
  }
  ssq1 += __shfl_xor(ssq1, 16); md1 += __shfl_xor(md1, 16);
  ssq2 += __shfl_xor(ssq2, 16); md2 += __shfl_xor(md2, 16);
  ssq1 += __shfl_xor(ssq1, 32); md1 += __shfl_xor(md1, 32);
  ssq2 += __shfl_xor(ssq2, 32); md2 += __shfl_xor(md2, 32);

  const float mu1 = md1 * (1.f / TS), mu2 = md2 * (1.f / TS);
  const float va1 = (ssq1 - (float)TS * mu1 * mu1) * (1.f / (TS - 1));
  const float va2 = (ssq2 - (float)TS * mu2 * mu2) * (1.f / (TS - 1));
  const float iv1 = 1.f / (sqrtf(fmaxf(va1, 0.f)) + EPSV);
  const float iv2 = 1.f / (sqrtf(fmaxf(va2, 0.f)) + EPSV);
  __syncthreads();                   // release p_s (Q) + kbuf[1] (Q2)

  // ---- kv loop, unrolled x2 for static K2 reg buffers ----
  float lrow = 0.f;
  f32x4 accO[4] = {};                // lane: row = wr*16 + l4*4+e, d = ni*16+l15

  // one tile's compute: QK^T (K from LDS, K2 from regs) -> softmax -> P -> PV
#define COMPUTE_TILE(ti, KS_, VS_, K2F)                                         \
  {                                                                             \
    const int t0 = (ti) * 64;                                                   \
    f32x4 a1[2] = {}, a2[2] = {};                                               \
    _Pragma("unroll")                                                           \
    for (int ks = 0; ks < 2; ++ks) {                                            \
      bf16x8 bk[2];                                                             \
      _Pragma("unroll")                                                         \
      for (int ni = 0; ni < 2; ++ni) {                                          \
        int j  = p * 32 + ni * 16 + l15;                                        \
        int gg = ((ks * 4 + l4) ^ (j & 7)) * 8;                                 \
        bk[ni] = *(const bf16x8*)&KS_[j * 64 + gg];                             \
      }                                                                         \
      _Pragma("unroll")                                                         \
      for (int ni = 0; ni < 2; ++ni) {                                          \
        a1[ni] = MFMA(bk[ni], fq[ks], a1[ni]);                                  \
        a2[ni] = MFMA(K2F[ni][ks], fq2[ks], a2[ni]);                            \
      }                                                                         \
    }                                                                           \
    const int grow = m0 + qrow;                                                 \
    _Pragma("unroll")                                                           \
    for (int ni = 0; ni < 2; ++ni) {                                            \
      float pe[4];                                                              \
      _Pragma("unroll")                                                         \
      for (int e = 0; e < 4; ++e) {                                             \
        float n1 = (a1[ni][e] - mu1) * iv1;                                     \
        float n2 = (a2[ni][e] - mu2) * iv2;                                     \
        float sc = n1 * fmaf(mq2, n2, om2);                                     \
        float pv = exp2f(sc);                                                   \
        int gcol = t0 + p * 32 + ni * 16 + l4 * 4 + e;                          \
        pv = (gcol <= grow) ? pv : 0.f;                                         \
        lrow += pv;                                                             \
        pe[e] = pv;                                                             \
      }                                                                         \
      uint32_t pk01, pk23;                                                      \
      asm("v_cvt_pk_bf16_f32 %0, %1, %2" : "=v"(pk01) : "v"(pe[0]), "v"(pe[1]));\
      asm("v_cvt_pk_bf16_f32 %0, %1, %2" : "=v"(pk23) : "v"(pe[2]), "v"(pe[3]));\
      uint2 pk; pk.x = pk01; pk.y = pk23;                                       \
      *(uint2*)&p_s[p * 1280 + qrow * 40 + ni * 16 + l4 * 4] = pk;              \
    }                                                                           \
    {                                                                           \
      bf16x8 ap = *(const bf16x8*)&p_s[p * 1280 + qrow * 40 + l4 * 8];          \
      _Pragma("unroll")                                                         \
      for (int ni = 0; ni < 4; ++ni) {                                          \
        int d  = ni * 16 + l15;                                                 \
        int gg = ((p * 4 + l4) ^ (d & 7)) * 8;                                  \
        bf16x8 bv = *(const bf16x8*)&VS_[d * 64 + gg];                          \
        accO[ni] = MFMA(ap, bv, accO[ni]);                                      \
      }                                                                         \
    }                                                                           \
  }

  for (int ii = 0; ii < nkv; ii += 2) {
    // even tile ii: LDS buf 0, K2 regs k2A
    if (ii + 1 < nkv) {
      stage_k(ii + 1, 1); stage_v(ii + 1, 1);
      LOAD_K2(ii + 1, k2B);
    }
    COMPUTE_TILE(ii, kbuf[0], vbuf[0], k2A);
    __syncthreads();   // drains prefetches (incl. k2B global loads) + releases buf0
    if (ii + 1 >= nkv) break;

    // odd tile ii+1: LDS buf 1, K2 regs k2B
    if (ii + 2 < nkv) {
      stage_k(ii + 2, 0); stage_v(ii + 2, 0);
      LOAD_K2(ii + 2, k2A);
    }
    COMPUTE_TILE(ii + 1, kbuf[1], vbuf[1], k2B);
    __syncthreads();
  }
#undef COMPUTE_TILE
#undef LOAD_K2

  // ---- epilogue: combine wave pairs (additive, no-max), normalize, write ----
  lrow += __shfl_xor(lrow, 16);
  lrow += __shfl_xor(lrow, 32);      // row-sum of this pair's kv half

  float* fb = (float*)kbuf;          // [32][64] f32 partial O (8KB of 16KB)
  float* fl = (float*)vbuf;          // [32] f32 partial lrow
  if (p == 1) {
    #pragma unroll
    for (int ni = 0; ni < 4; ++ni)
      #pragma unroll
      for (int e = 0; e < 4; ++e)
        fb[(wr * 16 + l4 * 4 + e) * 64 + ni * 16 + l15] = accO[ni][e];
    if (l4 == 0) fl[qrow] = lrow;
  }
  __syncthreads();
  if (p == 0) {
    float lt = lrow + fl[qrow];      // total row denom (lane l15-indexed)
    float il[4];
    #pragma unroll
    for (int e = 0; e < 4; ++e)
      il[e] = 1.f / __shfl(lt, l4 * 4 + e);
    #pragma unroll
    for (int ni = 0; ni < 4; ++ni)
      #pragma unroll
      for (int e = 0; e < 4; ++e) {
        float o = accO[ni][e] + fb[(wr * 16 + l4 * 4 + e) * 64 + ni * 16 + l15];
        Y[(size_t)(m0 + wr * 16 + l4 * 4 + e) * CS + ni * 16 + l15] = f2bf(o * il[e]);
      }
  }
}

// ---------------- launcher ----------------
extern "C" void kernel_launch(void* const* d_in, const int* in_sizes, int n_in,
                              void* d_out, int out_size, void* d_ws, size_t ws_size,
                              hipStream_t stream) {
  const float* x    = (const float*)d_in[0];
  const float* Wq   = (const float*)d_in[1];
  const float* Wk   = (const float*)d_in[2];
  const float* Wv   = (const float*)d_in[3];
  const float* Wq2  = (const float*)d_in[4];
  const float* Wk2  = (const float*)d_in[5];
  const float* Wo   = (const float*)d_in[6];
  const float* mixture = (const float*)d_in[7];
  const float* qsc  = (const float*)d_in[8];
  float* out = (float*)d_out;

  ushort* ws = (ushort*)d_ws;
  ushort* xb   = ws;                                  // 2M
  ushort* wcat = xb   + (size_t)2 * MEG;              // 6M: wq,wk,wq2,wk2,wv,wo
  ushort* qb   = wcat + (size_t)6 * MEG;              // 2M (pre-scaled by 1/8)
  ushort* q2b  = qb   + (size_t)2 * MEG;              // 2M (pre-scaled by 1/8)
  ushort* kb   = q2b  + (size_t)2 * MEG;              // 2M
  ushort* k2b  = kb   + (size_t)2 * MEG;              // 2M
  ushort* vtb  = k2b  + (size_t)2 * MEG;              // 2M  [B*NH][64][T]
  ushort* yb   = vtb  + (size_t)2 * MEG;              // 2M
  ushort* ktb  = yb   + (size_t)2 * MEG;              // 2M  [B*NH][64][T]
  ushort* k2tb = ktb  + (size_t)2 * MEG;              // 2M
  ushort* g1b  = k2tb + (size_t)2 * MEG;              // 128K: [32][64][64] bf16
  ushort* g2b  = g1b  + (size_t)(MEG / 8);            // 128K
  float*  csb  = (float*)(g2b + (size_t)(MEG / 8));   // [2][32][64] fp32
  ushort* wob  = wcat + (size_t)5 * MEG;

  // 1. cast everything to bf16
  cast_all<<<2048, 256, 0, stream>>>(x, Wq, Wk, Wv, Wq2, Wk2, Wo, xb, wcat);

  // 2. fused projections (+ transposed K, K2 for gram), BM=64/BK=64, 1280 blocks
  gemm_proj<<<1280, 256, 0, stream>>>(
      xb, wcat, qb, kb, q2b, k2b, vtb, ktb, k2tb);

  // 3. Gram matrices + colsums
  gram<<<64, 256, 0, stream>>>(ktb, k2tb, g1b, g2b, csb);

  // 4. fused attention (1024 blocks, K2-in-regs, 37KB LDS)
  attn_fused<<<1024, 256, 0, stream>>>(qb, kb, q2b, k2b, vtb, yb,
                                       g1b, g2b, csb, mixture, qsc);

  // 5. output projection (fp32 out), 512 blocks, BK=64
  gemm_out<<<512, 256, 0, stream>>>(yb, wob, out);
}

// Round 15
// 99.507 us; speedup vs baseline: 1.1602x; 1.0533x over previous
//
#include <hip/hip_runtime.h>
#include <hip/hip_bf16.h>
#include <stdint.h>

#define TS 1024   // T
#define CS 1024   // C
#define NH 16
#define DHEAD 64
#define NBATCH 2
#define EPSV 1e-5f
#define MEG 1048576

typedef __bf16 bf16x8 __attribute__((ext_vector_type(8)));
typedef float  f32x4  __attribute__((ext_vector_type(4)));

#define MFMA(a, b, c) __builtin_amdgcn_mfma_f32_16x16x32_bf16((a), (b), (c), 0, 0, 0)

__device__ __forceinline__ float bf2f(ushort u){
  union { uint32_t i; float f; } v; v.i = ((uint32_t)u) << 16; return v.f;
}
__device__ __forceinline__ ushort f2bf(float f){
  union { float f; uint32_t i; } v; v.f = f;
  uint32_t r = v.i + 0x7FFFu + ((v.i >> 16) & 1u);
  return (ushort)(r >> 16);
}

// async global->LDS, 16B per lane. LDS dest wave-uniform base + lane*16B (linear);
// global src per-lane (enables pre-swizzled-source LDS layouts).
__device__ __forceinline__ void gl_lds16(const ushort* g, ushort* l) {
  __builtin_amdgcn_global_load_lds(
      (const __attribute__((address_space(1))) void*)g,
      (__attribute__((address_space(3))) void*)l, 16, 0, 0);
}

// ---------------- fused cast fp32 -> bf16 of all 7 tensors ----------------
__global__ __launch_bounds__(256)
void cast_all(const float* __restrict__ x,
              const float* __restrict__ Wq, const float* __restrict__ Wk,
              const float* __restrict__ Wv, const float* __restrict__ Wq2,
              const float* __restrict__ Wk2, const float* __restrict__ Wo,
              ushort* __restrict__ xb, ushort* __restrict__ wcat)
{
  const int XC = 524288, TOT = 2097152;
  for (int idx = blockIdx.x * 256 + threadIdx.x; idx < TOT; idx += 524288) {
    const float* s; ushort* d; int c;
    if (idx < XC) { s = x; d = xb; c = idx; }
    else {
      int r = idx - XC; int w = r >> 18; c = r & 262143;
      switch (w) {
        case 0:  s = Wq;  d = wcat;           break;
        case 1:  s = Wk;  d = wcat + 1*MEG;   break;
        case 2:  s = Wv;  d = wcat + 4*MEG;   break;
        case 3:  s = Wq2; d = wcat + 2*MEG;   break;
        case 4:  s = Wk2; d = wcat + 3*MEG;   break;
        default: s = Wo;  d = wcat + 5*MEG;   break;
      }
    }
    float4 v = *(const float4*)(s + (size_t)c * 4);
    ushort4 o; o.x = f2bf(v.x); o.y = f2bf(v.y); o.z = f2bf(v.z); o.w = f2bf(v.w);
    *(ushort4*)(d + (size_t)c * 4) = o;
  }
}

#define BN 128

// ---------------- fused projection GEMM: [x]@[Wq;Wk;Wq2;Wk2;Wv]^T ----------------
// BM=64 x BN=128, BK=64, single-buffered (24KB LDS, high block-TLP hides the
// barrier drain; explicit dbuf at 64KB measured WORSE). 1D grid 1280, XCD-swizzled.
__global__ __launch_bounds__(256, 2)
void gemm_proj(const ushort* __restrict__ A, const ushort* __restrict__ Bt,
               ushort* __restrict__ qb, ushort* __restrict__ kb,
               ushort* __restrict__ q2b, ushort* __restrict__ k2b,
               ushort* __restrict__ vtb,
               ushort* __restrict__ ktb, ushort* __restrict__ k2tb)
{
  __shared__ ushort a_s[64 * 64];    // [64 rows][64 cols] swz g^=row&7 (8KB)
  __shared__ ushort b_s[128 * 64];   // 16KB

  const int bid = blockIdx.x;
  const int s   = (bid & 7) * 160 + (bid >> 3);   // bijective, 1280%8==0
  const int n0  = (s >> 5) * BN;                  // x in [5c, 5c+5) per XCD c
  const int m0  = (s & 31) * 64;

  const int t  = threadIdx.x;
  const int w  = t >> 6, l = t & 63;
  const int wr = w >> 1, wc = w & 1;
  const int l15 = l & 15, l4 = l >> 4;
  const int r8 = l >> 3, g7 = l & 7;

  f32x4 acc[2][4] = {};

  for (int k0 = 0; k0 < CS; k0 += 64) {
    #pragma unroll
    for (int i = 0; i < 2; ++i) {
      int issue = w * 2 + i;              // 0..7
      int row   = issue * 8 + r8;         // 0..63
      int gs    = g7 ^ (row & 7);
      gl_lds16(&A[(size_t)(m0 + row) * CS + k0 + gs * 8], &a_s[issue * 512]);
    }
    #pragma unroll
    for (int i = 0; i < 4; ++i) {
      int issue = w * 4 + i;              // 0..15
      int row   = issue * 8 + r8;         // 0..127
      int gs    = g7 ^ (row & 7);
      gl_lds16(&Bt[(size_t)(n0 + row) * CS + k0 + gs * 8], &b_s[issue * 512]);
    }
    __syncthreads();

    #pragma unroll
    for (int ks = 0; ks < 2; ++ks) {
      bf16x8 af[2], bfr[4];
      #pragma unroll
      for (int mi = 0; mi < 2; ++mi) {
        int row = wr * 32 + mi * 16 + l15;
        int gl  = (ks * 4 + l4) ^ (row & 7);
        af[mi] = *(const bf16x8*)&a_s[row * 64 + gl * 8];
      }
      #pragma unroll
      for (int ni = 0; ni < 4; ++ni) {
        int row = wc * 64 + ni * 16 + l15;
        int gl  = (ks * 4 + l4) ^ (row & 7);
        bfr[ni] = *(const bf16x8*)&b_s[row * 64 + gl * 8];
      }
      #pragma unroll
      for (int mi = 0; mi < 2; ++mi)
        #pragma unroll
        for (int ni = 0; ni < 4; ++ni)
          acc[mi][ni] = MFMA(af[mi], bfr[ni], acc[mi][ni]);
    }

    __syncthreads();
  }

  #pragma unroll
  for (int mi = 0; mi < 2; ++mi) {
    #pragma unroll
    for (int ni = 0; ni < 4; ++ni) {
      int col  = n0 + wc * 64 + ni * 16 + l15;
      int row0 = m0 + wr * 32 + mi * 16 + l4 * 4;
      int seg  = col >> 10, cc = col & (CS - 1);
      if (seg < 4) {
        ushort* dst = (seg == 0) ? qb : (seg == 1) ? kb : (seg == 2) ? q2b : k2b;
        float sc = (seg & 1) ? 1.f : 0.125f;   // fold 1/sqrt(Dh) into q, q2
        #pragma unroll
        for (int e = 0; e < 4; ++e)
          dst[(size_t)(row0 + e) * CS + cc] = f2bf(acc[mi][ni][e] * sc);
        if (seg == 1 || seg == 3) {
          int bb = row0 >> 10, tt = row0 & (TS - 1);
          int hh = cc >> 6, dd = cc & (DHEAD - 1);
          ushort* td = (seg == 1) ? ktb : k2tb;
          ushort4 o;
          o.x = f2bf(acc[mi][ni][0]); o.y = f2bf(acc[mi][ni][1]);
          o.z = f2bf(acc[mi][ni][2]); o.w = f2bf(acc[mi][ni][3]);
          *(ushort4*)&td[(((size_t)(bb * NH + hh) * DHEAD + dd) * TS) + tt] = o;
        }
      } else {
        int bb = row0 >> 10, tt = row0 & (TS - 1);
        int hh = cc >> 6, dd = cc & (DHEAD - 1);
        ushort4 o;
        o.x = f2bf(acc[mi][ni][0]); o.y = f2bf(acc[mi][ni][1]);
        o.z = f2bf(acc[mi][ni][2]); o.w = f2bf(acc[mi][ni][3]);
        *(ushort4*)&vtb[(((size_t)(bb * NH + hh) * DHEAD + dd) * TS) + tt] = o;
      }
    }
  }
}

// ---------------- out-projection GEMM: out = y @ Wo^T (fp32 out) --------------
// BM=64 x BN=64, BK=64, granule-XOR swizzled LDS. Grid 512, 1D XCD-swizzled.
__global__ __launch_bounds__(256, 2)
void gemm_out(const ushort* __restrict__ A, const ushort* __restrict__ Bt,
              float* __restrict__ C)
{
  __shared__ ushort a_s[64 * 64];   // 8KB, swz g^=row&7
  __shared__ ushort b_s[64 * 64];   // 8KB

  const int bid = blockIdx.x;
  const int s   = (bid & 7) * 64 + (bid >> 3);    // bijective, 512%8==0
  const int n0  = (s >> 5) * 64;
  const int m0  = (s & 31) * 64;

  const int t  = threadIdx.x;
  const int w  = t >> 6, l = t & 63;
  const int wr = w >> 1, wc = w & 1;
  const int l15 = l & 15, l4 = l >> 4;
  const int r8 = l >> 3, g7 = l & 7;

  f32x4 acc[2][2] = {};

  for (int k0 = 0; k0 < CS; k0 += 64) {
    #pragma unroll
    for (int i = 0; i < 2; ++i) {
      int issue = w * 2 + i;              // 0..7
      int row   = issue * 8 + r8;         // 0..63
      int gs    = g7 ^ (row & 7);
      gl_lds16(&A [(size_t)(m0 + row) * CS + k0 + gs * 8], &a_s[issue * 512]);
      gl_lds16(&Bt[(size_t)(n0 + row) * CS + k0 + gs * 8], &b_s[issue * 512]);
    }
    __syncthreads();

    #pragma unroll
    for (int ks = 0; ks < 2; ++ks) {
      bf16x8 af[2], bfr[2];
      #pragma unroll
      for (int mi = 0; mi < 2; ++mi) {
        int row = wr * 32 + mi * 16 + l15;
        int gl  = (ks * 4 + l4) ^ (row & 7);
        af[mi] = *(const bf16x8*)&a_s[row * 64 + gl * 8];
      }
      #pragma unroll
      for (int ni = 0; ni < 2; ++ni) {
        int row = wc * 32 + ni * 16 + l15;
        int gl  = (ks * 4 + l4) ^ (row & 7);
        bfr[ni] = *(const bf16x8*)&b_s[row * 64 + gl * 8];
      }
      #pragma unroll
      for (int mi = 0; mi < 2; ++mi)
        #pragma unroll
        for (int ni = 0; ni < 2; ++ni)
          acc[mi][ni] = MFMA(af[mi], bfr[ni], acc[mi][ni]);
    }

    __syncthreads();
  }

  #pragma unroll
  for (int mi = 0; mi < 2; ++mi)
    #pragma unroll
    for (int ni = 0; ni < 2; ++ni)
      #pragma unroll
      for (int e = 0; e < 4; ++e)
        C[(size_t)(m0 + wr * 32 + mi * 16 + l4 * 4 + e) * CS +
          n0 + wc * 32 + ni * 16 + l15] = acc[mi][ni][e];
}

// ---------------- Gram kernel: G = K^T K (64x64, bf16 out) + colsum(K) ----------
__global__ __launch_bounds__(256, 2)
void gram(const ushort* __restrict__ ktb, const ushort* __restrict__ k2tb,
          ushort* __restrict__ g1b, ushort* __restrict__ g2b,
          float* __restrict__ csb)
{
  __shared__ ushort t_s[64 * 128];   // [64 d][128 t], granule-swizzled g ^= d&15

  const int mat = blockIdx.x & 1, z = blockIdx.x >> 1;
  const ushort* S = (mat ? k2tb : ktb) + (size_t)z * DHEAD * TS;

  const int t = threadIdx.x, w = t >> 6, l = t & 63;
  const int l15 = l & 15, l4 = l >> 4;

  f32x4 acc[4] = {};
  float csacc = 0.f;

  for (int tt = 0; tt < 8; ++tt) {
    const int t0 = tt * 128;
    __syncthreads();
    #pragma unroll
    for (int i = 0; i < 4; ++i) {
      int issue = w * 4 + i;
      int row = issue * 4 + l4;
      int gs  = l15 ^ (row & 15);
      gl_lds16(&S[(size_t)row * TS + t0 + gs * 8], &t_s[issue * 512]);
    }
    __syncthreads();

    {
      int r = w * 16 + l15;
      #pragma unroll
      for (int j = 0; j < 4; ++j) {
        int gg = ((l4 * 4 + j) ^ (r & 15)) * 8;
        uint4 vv = *(const uint4*)&t_s[r * 128 + gg];
        const ushort* pu = (const ushort*)&vv;
        #pragma unroll
        for (int e2 = 0; e2 < 8; ++e2) csacc += bf2f(pu[e2]);
      }
    }

    #pragma unroll
    for (int ks = 0; ks < 4; ++ks) {
      int ar = w * 16 + l15;
      bf16x8 af = *(const bf16x8*)&t_s[ar * 128 + ((ks * 4 + l4) ^ (ar & 15)) * 8];
      #pragma unroll
      for (int ni = 0; ni < 4; ++ni) {
        int br = ni * 16 + l15;
        bf16x8 bf_ = *(const bf16x8*)&t_s[br * 128 + ((ks * 4 + l4) ^ (br & 15)) * 8];
        acc[ni] = MFMA(af, bf_, acc[ni]);
      }
    }
  }

  csacc += __shfl_xor(csacc, 16);
  csacc += __shfl_xor(csacc, 32);
  if (l4 == 0)
    csb[(mat * 32 + z) * 64 + w * 16 + l15] = csacc;

  ushort* G = (mat ? g2b : g1b) + (size_t)z * 4096;
  #pragma unroll
  for (int ni = 0; ni < 4; ++ni)
    #pragma unroll
    for (int e = 0; e < 4; ++e)
      G[(w * 16 + l4 * 4 + e) * 64 + ni * 16 + l15] = f2bf(acc[ni][e]);
}

// ---------------- fused attention v11: 64-row Q-tiles, wave-owns-16-rows -------
// 512 blocks (head z x q64-tile). Wave w owns q-rows [w*16,+16) x FULL 64-kv
// tile: barrier-iterations HALVE (each staged K/K2/V tile feeds 2x the Q rows),
// per-iter MFMA per wave doubles (24) so the drain hides better, and the
// epilogue cross-wave merge disappears (lrow/accO fully wave-local).
// No-max softmax (z-scored scores bounded), Gram-trick stats.
// LDS = K dbuf 16K + K2 dbuf 16K + V dbuf 16K + P 9K = 57KB; grid 2 blocks/CU.
// Complementary pairing (15-qq, qq): per-CU iteration sums = 17 for every CU.
__global__ __launch_bounds__(256, 2)
void attn_fused(const ushort* __restrict__ qb, const ushort* __restrict__ kb,
                const ushort* __restrict__ q2b, const ushort* __restrict__ k2b,
                const ushort* __restrict__ vtb, ushort* __restrict__ yb,
                const ushort* __restrict__ g1b, const ushort* __restrict__ g2b,
                const float* __restrict__ csb,
                const float* __restrict__ mixture, const float* __restrict__ qsc)
{
  __shared__ ushort kbuf [2][4096];  // K tile [64 kv][64 d] swz g^=kv&7 (buf1: Q in prologue)
  __shared__ ushort k2buf[2][4096];  // K2 tile                          (buf1: Q2 in prologue)
  __shared__ ushort vbuf [2][4096];  // V tile [64 d][64 kv] swz g^=d&7
  __shared__ ushort p_s  [64 * 72];  // P [64 r][72] (64 + 8 pad -> 2-way banks max)

  const int idx  = blockIdx.x;
  const int pp   = idx >> 8;                     // 0..1 sweep
  const int base = idx & 255;
  const int xcd  = base & 7;
  const int mm   = base >> 3;                    // 0..31
  const int qq   = mm & 7;
  const int z    = (mm >> 3) * 8 + xcd;          // head id, affine to XCD
  const int q64  = pp ? qq : (15 - qq);          // pair (15-qq, qq): per-CU sum 17
  const int b    = z >> 4, h = z & 15;
  const int m0   = q64 * 64;
  const int nkv  = q64 + 1;                      // # 64-kv tiles (causal)

  const ushort* Q  = qb  + (size_t)b * TS * CS + h * DHEAD;
  const ushort* Q2 = q2b + (size_t)b * TS * CS + h * DHEAD;
  const ushort* K  = kb  + (size_t)b * TS * CS + h * DHEAD;
  const ushort* K2 = k2b + (size_t)b * TS * CS + h * DHEAD;
  const ushort* Vt = vtb + (size_t)z * DHEAD * TS;
  const ushort* G1 = g1b + (size_t)z * 4096;
  const ushort* G2 = g2b + (size_t)z * 4096;
  ushort* Y = yb + (size_t)b * TS * CS + h * DHEAD;

  const int t = threadIdx.x, w = t >> 6, l = t & 63;
  const int l15 = l & 15, l4 = l >> 4;
  const int r8 = l >> 3, g7 = l & 7;
  const int qrow = w * 16 + l15;                 // this wave's q-row (local 0..63)

  const float L2E = 1.44269504f;
  const float gm = 1.f / (1.f + __expf(-mixture[0]));
  const float mq2 = gm * qsc[0] * L2E;
  const float om2 = (1.f - gm) * L2E;

  auto stage_k = [&](int ti, int bs) {
    const int t0 = ti * 64;
    #pragma unroll
    for (int i = 0; i < 2; ++i) {
      int issue = w * 2 + i;
      int row = issue * 8 + r8;                  // kv row 0..63
      int gs  = g7 ^ (row & 7);
      gl_lds16(&K [(size_t)(t0 + row) * CS + gs * 8], &kbuf [bs][issue * 512]);
      gl_lds16(&K2[(size_t)(t0 + row) * CS + gs * 8], &k2buf[bs][issue * 512]);
    }
  };
  auto stage_v = [&](int ti, int bs) {
    const int t0 = ti * 64;
    #pragma unroll
    for (int i = 0; i < 2; ++i) {
      int issue = w * 2 + i;
      int row = issue * 8 + r8;                  // d row 0..63
      int gs  = g7 ^ (row & 7);
      gl_lds16(&Vt[(size_t)row * TS + t0 + gs * 8], &vbuf[bs][issue * 512]);
    }
  };

  // ---- prologue: Q -> kbuf[1], Q2 -> k2buf[1]; K0/K2_0 -> buf0, V0 -> vbuf0 ----
  #pragma unroll
  for (int i = 0; i < 2; ++i) {
    int issue = w * 2 + i;
    int row = issue * 8 + r8;                    // 0..63
    int gs  = g7 ^ (row & 7);
    gl_lds16(&Q [(size_t)(m0 + row) * CS + gs * 8], &kbuf [1][issue * 512]);
    gl_lds16(&Q2[(size_t)(m0 + row) * CS + gs * 8], &k2buf[1][issue * 512]);
  }
  stage_k(0, 0);
  stage_v(0, 0);
  __syncthreads();

  // Q fragments (B-operand: wave's 16 rows over l15, k-slice over l4)
  bf16x8 fq[2], fq2[2];
  #pragma unroll
  for (int ks = 0; ks < 2; ++ks) {
    int gg = ((ks * 4 + l4) ^ (qrow & 7)) * 8;
    fq [ks] = *(const bf16x8*)&kbuf [1][qrow * 64 + gg];
    fq2[ks] = *(const bf16x8*)&k2buf[1][qrow * 64 + gg];
  }

  // U = G @ Q^T (G from global, row-major A-frags); lane: d = ni*16+l4*4+e, col=qrow
  f32x4 U1[4] = {}, U2[4] = {};
  #pragma unroll
  for (int ks = 0; ks < 2; ++ks)
    #pragma unroll
    for (int ni = 0; ni < 4; ++ni) {
      bf16x8 bg = *(const bf16x8*)&G1[(ni * 16 + l15) * 64 + ks * 32 + l4 * 8];
      U1[ni] = MFMA(bg, fq[ks], U1[ni]);
    }
  #pragma unroll
  for (int ks = 0; ks < 2; ++ks)
    #pragma unroll
    for (int ni = 0; ni < 4; ++ni) {
      bf16x8 bg = *(const bf16x8*)&G2[(ni * 16 + l15) * 64 + ks * 32 + l4 * 8];
      U2[ni] = MFMA(bg, fq2[ks], U2[ni]);
    }

  // per-lane stats: ssq = sum_d U[d]*q[d]; mudot = sum_d q[d]*cs[d]
  float ssq1 = 0.f, md1 = 0.f, ssq2 = 0.f, md2 = 0.f;
  #pragma unroll
  for (int ni = 0; ni < 4; ++ni) {
    int gsq = (ni * 2 + (l4 >> 1)) ^ (qrow & 7);
    int off = qrow * 64 + gsq * 8 + (l4 & 1) * 4;
    ushort qa[4], qb2[4];
    *(uint2*)qa  = *(const uint2*)&kbuf [1][off];
    *(uint2*)qb2 = *(const uint2*)&k2buf[1][off];
    float c1[4], c2[4];
    *(float4*)c1 = *(const float4*)&csb[z * 64 + ni * 16 + l4 * 4];
    *(float4*)c2 = *(const float4*)&csb[2048 + z * 64 + ni * 16 + l4 * 4];
    #pragma unroll
    for (int e = 0; e < 4; ++e) {
      float qv1 = bf2f(qa[e]), qv2 = bf2f(qb2[e]);
      ssq1 = fmaf(U1[ni][e], qv1, ssq1); md1 = fmaf(qv1, c1[e], md1);
      ssq2 = fmaf(U2[ni][e], qv2, ssq2); md2 = fmaf(qv2, c2[e], md2);
    }
  }
  ssq1 += __shfl_xor(ssq1, 16); md1 += __shfl_xor(md1, 16);
  ssq2 += __shfl_xor(ssq2, 16); md2 += __shfl_xor(md2, 16);
  ssq1 += __shfl_xor(ssq1, 32); md1 += __shfl_xor(md1, 32);
  ssq2 += __shfl_xor(ssq2, 32); md2 += __shfl_xor(md2, 32);

  const float mu1 = md1 * (1.f / TS), mu2 = md2 * (1.f / TS);
  const float va1 = (ssq1 - (float)TS * mu1 * mu1) * (1.f / (TS - 1));
  const float va2 = (ssq2 - (float)TS * mu2 * mu2) * (1.f / (TS - 1));
  const float iv1 = 1.f / (sqrtf(fmaxf(va1, 0.f)) + EPSV);
  const float iv2 = 1.f / (sqrtf(fmaxf(va2, 0.f)) + EPSV);
  __syncthreads();                   // release kbuf[1]/k2buf[1] (Q/Q2 read done)

  // ---- kv loop: prefetch K/K2/V(i+1) -> QK^T -> softmax -> PV -> ONE barrier ----
  float lrow = 0.f;
  f32x4 accO[4] = {};                // lane: row = w*16 + l4*4+e, d = ni*16+l15

  for (int i = 0; i < nkv; ++i) {
    const int t0  = i * 64;
    const int cur = i & 1;
    if (i + 1 < nkv) { stage_k(i + 1, cur ^ 1); stage_v(i + 1, cur ^ 1); }

    const ushort* ks_ = kbuf [cur];
    const ushort* k2s_= k2buf[cur];

    // QK^T swapped: A = K rows (full 64 kv), B = Q rows; kv = ni*16+l4*4+e
    f32x4 a1[4] = {}, a2[4] = {};
    #pragma unroll
    for (int ks = 0; ks < 2; ++ks) {
      bf16x8 bk[4], bk2[4];
      #pragma unroll
      for (int ni = 0; ni < 4; ++ni) {
        int j  = ni * 16 + l15;
        int gg = ((ks * 4 + l4) ^ (j & 7)) * 8;
        bk [ni] = *(const bf16x8*)&ks_ [j * 64 + gg];
        bk2[ni] = *(const bf16x8*)&k2s_[j * 64 + gg];
      }
      #pragma unroll
      for (int ni = 0; ni < 4; ++ni) {
        a1[ni] = MFMA(bk [ni], fq [ks], a1[ni]);
        a2[ni] = MFMA(bk2[ni], fq2[ks], a2[ni]);
      }
    }

    // normalize + gate + causal mask + exp2; pack & store P (wave-local rows)
    const int grow = m0 + qrow;
    #pragma unroll
    for (int ni = 0; ni < 4; ++ni) {
      float pe[4];
      #pragma unroll
      for (int e = 0; e < 4; ++e) {
        float n1 = (a1[ni][e] - mu1) * iv1;
        float n2 = (a2[ni][e] - mu2) * iv2;
        float sc = n1 * fmaf(mq2, n2, om2);
        float pv = exp2f(sc);
        int gcol = t0 + ni * 16 + l4 * 4 + e;
        pv = (gcol <= grow) ? pv : 0.f;
        lrow += pv;
        pe[e] = pv;
      }
      uint32_t pk01, pk23;
      asm("v_cvt_pk_bf16_f32 %0, %1, %2" : "=v"(pk01) : "v"(pe[0]), "v"(pe[1]));
      asm("v_cvt_pk_bf16_f32 %0, %1, %2" : "=v"(pk23) : "v"(pe[2]), "v"(pe[3]));
      uint2 pk; pk.x = pk01; pk.y = pk23;
      *(uint2*)&p_s[qrow * 72 + ni * 16 + l4 * 4] = pk;
    }

    // PV: A = P[wave's 16 rows][64 kv], B = V[d][64 kv]; same-wave LDS dep
    #pragma unroll
    for (int ks = 0; ks < 2; ++ks) {
      bf16x8 ap = *(const bf16x8*)&p_s[qrow * 72 + ks * 32 + l4 * 8];
      #pragma unroll
      for (int ni = 0; ni < 4; ++ni) {
        int d  = ni * 16 + l15;
        int gg = ((ks * 4 + l4) ^ (d & 7)) * 8;
        bf16x8 bv = *(const bf16x8*)&vbuf[cur][d * 64 + gg];
        accO[ni] = MFMA(ap, bv, accO[ni]);
      }
    }

    __syncthreads();   // drains prefetches + releases cur buffers
  }

  // ---- epilogue: all wave-local (no cross-wave merge) ----
  lrow += __shfl_xor(lrow, 16);
  lrow += __shfl_xor(lrow, 32);      // full row-sum for q-row l15
  float il[4];
  #pragma unroll
  for (int e = 0; e < 4; ++e)
    il[e] = 1.f / __shfl(lrow, l4 * 4 + e);    // lane r (r<16) holds row r's sum
  #pragma unroll
  for (int ni = 0; ni < 4; ++ni)
    #pragma unroll
    for (int e = 0; e < 4; ++e)
      Y[(size_t)(m0 + w * 16 + l4 * 4 + e) * CS + ni * 16 + l15] =
          f2bf(accO[ni][e] * il[e]);
}

// ---------------- launcher ----------------
extern "C" void kernel_launch(void* const* d_in, const int* in_sizes, int n_in,
                              void* d_out, int out_size, void* d_ws, size_t ws_size,
                              hipStream_t stream) {
  const float* x    = (const float*)d_in[0];
  const float* Wq   = (const float*)d_in[1];
  const float* Wk   = (const float*)d_in[2];
  const float* Wv   = (const float*)d_in[3];
  const float* Wq2  = (const float*)d_in[4];
  const float* Wk2  = (const float*)d_in[5];
  const float* Wo   = (const float*)d_in[6];
  const float* mixture = (const float*)d_in[7];
  const float* qsc  = (const float*)d_in[8];
  float* out = (float*)d_out;

  ushort* ws = (ushort*)d_ws;
  ushort* xb   = ws;                                  // 2M
  ushort* wcat = xb   + (size_t)2 * MEG;              // 6M: wq,wk,wq2,wk2,wv,wo
  ushort* qb   = wcat + (size_t)6 * MEG;              // 2M (pre-scaled by 1/8)
  ushort* q2b  = qb   + (size_t)2 * MEG;              // 2M (pre-scaled by 1/8)
  ushort* kb   = q2b  + (size_t)2 * MEG;              // 2M
  ushort* k2b  = kb   + (size_t)2 * MEG;              // 2M
  ushort* vtb  = k2b  + (size_t)2 * MEG;              // 2M  [B*NH][64][T]
  ushort* yb   = vtb  + (size_t)2 * MEG;              // 2M
  ushort* ktb  = yb   + (size_t)2 * MEG;              // 2M  [B*NH][64][T]
  ushort* k2tb = ktb  + (size_t)2 * MEG;              // 2M
  ushort* g1b  = k2tb + (size_t)2 * MEG;              // 128K: [32][64][64] bf16
  ushort* g2b  = g1b  + (size_t)(MEG / 8);            // 128K
  float*  csb  = (float*)(g2b + (size_t)(MEG / 8));   // [2][32][64] fp32
  ushort* wob  = wcat + (size_t)5 * MEG;

  // 1. cast everything to bf16
  cast_all<<<2048, 256, 0, stream>>>(x, Wq, Wk, Wv, Wq2, Wk2, Wo, xb, wcat);

  // 2. fused projections (+ transposed K, K2 for gram), BM=64/BK=64, 1280 blocks
  gemm_proj<<<1280, 256, 0, stream>>>(
      xb, wcat, qb, kb, q2b, k2b, vtb, ktb, k2tb);

  // 3. Gram matrices + colsums
  gram<<<64, 256, 0, stream>>>(ktb, k2tb, g1b, g2b, csb);

  // 4. fused attention (512 blocks, 64-row Q-tiles, halved barrier count)
  attn_fused<<<512, 256, 0, stream>>>(qb, kb, q2b, k2b, vtb, yb,
                                      g1b, g2b, csb, mixture, qsc);

  // 5. output projection (fp32 out), 512 blocks, BK=64
  gemm_out<<<512, 256, 0, stream>>>(yb, wob, out);
}